// Round 1
// baseline (2266.918 us; speedup 1.0000x reference)
//
#include <hip/hip_runtime.h>
#include <hip/hip_fp16.h>

#define BF 256      // B*F  (batch*frames)
#define TSTEPS 256  // time steps per clip
#define HDIM 128

typedef _Float16 h2v __attribute__((ext_vector_type(2)));

static __device__ __forceinline__ float fdot2f(unsigned int a, unsigned int b, float c) {
#if __has_builtin(__builtin_amdgcn_fdot2)
    union { unsigned int u; h2v v; } ca, cb;
    ca.u = a; cb.u = b;
    return __builtin_amdgcn_fdot2(ca.v, cb.v, c, false);
#else
    union { unsigned int u; __half2 h; } ca, cb;
    ca.u = a; cb.u = b;
    return c + __half2float(__low2half(ca.h)) * __half2float(__low2half(cb.h))
             + __half2float(__high2half(ca.h)) * __half2float(__high2half(cb.h));
#endif
}

static __device__ __forceinline__ float sigmoidf_(float x) {
    return 1.f / (1.f + __expf(-x));
}
// overflow-safe tanh: 1 - 2/(exp(2x)+1)  (no inf/inf NaN)
static __device__ __forceinline__ float tanhf_(float x) {
    return 1.f - 2.f / (__expf(2.f * x) + 1.f);
}

// ---------------- weight transpose: w[oc][ic][kh][kw] -> wT[ic*9+khw][oc] ----------
__global__ void transpose_w(const float* __restrict__ src, float* __restrict__ dst,
                            int OC, int IC) {
    int i = blockIdx.x * 256 + threadIdx.x;
    int n = OC * IC * 9;
    if (i >= n) return;
    int oc = i / (IC * 9);
    int rem = i % (IC * 9);
    dst[rem * OC + oc] = src[i];
}

// ---------------- Whh f16 pack: P[dir][k2][col] = half2(W[col][2k2], W[col][2k2+1]) --
__global__ void pack_whh(const float* __restrict__ Wf, const float* __restrict__ Wb,
                         unsigned int* __restrict__ P) {
    int i = blockIdx.x * 256 + threadIdx.x;
    if (i >= 2 * 64 * 512) return;
    int d  = i / (64 * 512);
    int r  = i % (64 * 512);
    int k2 = r / 512, col = r % 512;
    const float* W = d ? Wb : Wf;
    float a = W[col * 128 + k2 * 2];
    float b = W[col * 128 + k2 * 2 + 1];
    union { __half2 h; unsigned int u; } cv;
    cv.h = __floats2half2_rn(a, b);
    P[d * 64 * 512 + k2 * 512 + col] = cv.u;
}

// ---------------- direct conv, 16 t-outputs per thread ------------------------------
// in : [bf][IC][256][WIN], wT : [ic*9+khw][OC], out: normal [bf][OC][256][WOUT]
// or (OUT_TBC) X layout [t][bf][OC]
template<int IC, int OC, int WIN, int WOUT, bool OUT_TBC>
__global__ __launch_bounds__(256) void conv_k(const float* __restrict__ in,
                                              const float* __restrict__ wT,
                                              const float* __restrict__ bias,
                                              float* __restrict__ out) {
    int gid = blockIdx.x * 256 + threadIdx.x;
    const int total = BF * 16 * OC * WOUT;
    if (gid >= total) return;
    int ow  = gid % WOUT;
    int oc  = (gid / WOUT) % OC;
    int ohg = (gid / (WOUT * OC)) % 16;
    int bf  = gid / (WOUT * OC * 16);
    int t0  = ohg * 16;
    int iw0 = ow * 3 - 1;

    float acc[16];
#pragma unroll
    for (int i = 0; i < 16; i++) acc[i] = bias[oc];

    for (int ic = 0; ic < IC; ic++) {
        const float* ip = in + ((long)(bf * IC + ic) * TSTEPS) * WIN;
        float xw[18][3];
#pragma unroll
        for (int r = 0; r < 18; r++) {
            int ih = t0 + r - 1;
            bool hv = (unsigned)ih < (unsigned)TSTEPS;
#pragma unroll
            for (int c = 0; c < 3; c++) {
                int iw = iw0 + c;
                xw[r][c] = (hv && (unsigned)iw < (unsigned)WIN) ? ip[ih * WIN + iw] : 0.f;
            }
        }
#pragma unroll
        for (int kh = 0; kh < 3; kh++)
#pragma unroll
        for (int kw = 0; kw < 3; kw++) {
            float w = wT[(ic * 9 + kh * 3 + kw) * OC + oc];
#pragma unroll
            for (int t = 0; t < 16; t++) acc[t] += xw[t + kh][kw] * w;
        }
    }
#pragma unroll
    for (int t = 0; t < 16; t++) {
        float v = fmaxf(acc[t], 0.f);
        if (OUT_TBC) out[((long)(t0 + t) * BF + bf) * OC + oc] = v;
        else         out[((long)(bf * OC + oc) * TSTEPS + (t0 + t)) * WOUT + ow] = v;
    }
}

// ---------------- gates GEMM: G[row][col] = X[row]·Wih[col] + bih+bhh  (f16 out) ----
// rows = 65536 (t*256+b), cols: 0..511 fwd, 512..1023 bwd
__global__ __launch_bounds__(256) void gates_gemm(const float* __restrict__ X,
        const float* __restrict__ Wf, const float* __restrict__ Wb,
        const float* __restrict__ bf1, const float* __restrict__ bf2,
        const float* __restrict__ bb1, const float* __restrict__ bb2,
        __half* __restrict__ Gf, __half* __restrict__ Gb) {
    __shared__ float Xs[32][132];
    __shared__ float Ws[32][132];
    int tid = threadIdx.x;
    int r0 = blockIdx.x * 128;
    int c0 = blockIdx.y * 128;
    int tx = tid & 15, ty = tid >> 4;
    float acc[8][8] = {};
    int kk  = (tid & 7) * 4;
    int rr0 = tid >> 3;                       // 0..31

    for (int k0 = 0; k0 < 128; k0 += 32) {
#pragma unroll
        for (int p = 0; p < 4; p++) {
            int rr = rr0 + p * 32;
            float4 v = *(const float4*)&X[(long)(r0 + rr) * 128 + k0 + kk];
            Xs[kk + 0][rr] = v.x; Xs[kk + 1][rr] = v.y;
            Xs[kk + 2][rr] = v.z; Xs[kk + 3][rr] = v.w;
            int cg = c0 + rr;
            const float* Wsrc = (cg < 512) ? (Wf + (long)cg * 128)
                                           : (Wb + (long)(cg - 512) * 128);
            float4 w = *(const float4*)&Wsrc[k0 + kk];
            Ws[kk + 0][rr] = w.x; Ws[kk + 1][rr] = w.y;
            Ws[kk + 2][rr] = w.z; Ws[kk + 3][rr] = w.w;
        }
        __syncthreads();
#pragma unroll
        for (int k = 0; k < 32; k++) {
            float4 a0 = *(const float4*)&Xs[k][ty * 8];
            float4 a1 = *(const float4*)&Xs[k][ty * 8 + 4];
            float4 b0 = *(const float4*)&Ws[k][tx * 8];
            float4 b1 = *(const float4*)&Ws[k][tx * 8 + 4];
            float a[8] = {a0.x, a0.y, a0.z, a0.w, a1.x, a1.y, a1.z, a1.w};
            float b[8] = {b0.x, b0.y, b0.z, b0.w, b1.x, b1.y, b1.z, b1.w};
#pragma unroll
            for (int i = 0; i < 8; i++)
#pragma unroll
            for (int j = 0; j < 8; j++) acc[i][j] += a[i] * b[j];
        }
        __syncthreads();
    }
#pragma unroll
    for (int i = 0; i < 8; i++) {
        int r = r0 + ty * 8 + i;
#pragma unroll
        for (int j = 0; j < 8; j++) {
            int cg = c0 + tx * 8 + j;
            int cl = cg & 511;
            float bias = (cg < 512) ? (bf1[cl] + bf2[cl]) : (bb1[cl] + bb2[cl]);
            __half hv = __float2half(acc[i][j] + bias);
            ((cg < 512) ? Gf : Gb)[(long)r * 512 + cl] = hv;
        }
    }
}

// ---------------- LSTM recurrence: 1 block per (dir, batch-row) ---------------------
// thread owns gate cols tid and tid+256; Whh in f16-packed registers; h broadcast via LDS
__global__ __launch_bounds__(256) void lstm_k(const __half* __restrict__ Gf,
                                              const __half* __restrict__ Gb,
                                              const unsigned int* __restrict__ WhhP,
                                              float* __restrict__ flat) {
    int bid = blockIdx.x;
    int b   = bid & 255;
    int dir = bid >> 8;
    const __half* G = dir ? Gb : Gf;
    const unsigned int* WP = WhhP + dir * (64 * 512);
    int tid = threadIdx.x;
    int c0 = tid, c1 = tid + 256;

    unsigned int w0[64], w1[64];
#pragma unroll
    for (int i = 0; i < 64; i++) { w0[i] = WP[i * 512 + c0]; w1[i] = WP[i * 512 + c1]; }

    __shared__ uint4 h4[16];       // 128 halves of h
    __shared__ float zl[512];
    float cst = 0.f;
    if (tid < 16) h4[tid] = make_uint4(0u, 0u, 0u, 0u);
    __syncthreads();

    for (int t = 0; t < 256; t++) {
        int ts = dir ? (255 - t) : t;
        long row = (long)(ts * 256 + b) * 512;
        float z0 = __half2float(G[row + c0]);
        float z1 = __half2float(G[row + c1]);
#pragma unroll
        for (int i4 = 0; i4 < 16; i4++) {
            uint4 hp = h4[i4];
            z0 = fdot2f(hp.x, w0[i4 * 4 + 0], z0);
            z0 = fdot2f(hp.y, w0[i4 * 4 + 1], z0);
            z0 = fdot2f(hp.z, w0[i4 * 4 + 2], z0);
            z0 = fdot2f(hp.w, w0[i4 * 4 + 3], z0);
            z1 = fdot2f(hp.x, w1[i4 * 4 + 0], z1);
            z1 = fdot2f(hp.y, w1[i4 * 4 + 1], z1);
            z1 = fdot2f(hp.z, w1[i4 * 4 + 2], z1);
            z1 = fdot2f(hp.w, w1[i4 * 4 + 3], z1);
        }
        zl[c0] = z0; zl[c1] = z1;
        __syncthreads();
        if (tid < 128) {
            float ig = sigmoidf_(zl[tid]);
            float fg = sigmoidf_(zl[128 + tid]);
            float gg = tanhf_(zl[256 + tid]);
            float og = sigmoidf_(zl[384 + tid]);
            cst = fg * cst + ig * gg;
            float h = og * tanhf_(cst);
            ((__half*)h4)[tid] = __float2half(h);
            flat[(long)b * 65536 + ts * 256 + dir * 128 + tid] = h;
        }
        __syncthreads();
    }
}

// ---------------- FC1: z[256][128] += flat[256][65536] @ W[128][65536]^T (split-K) --
__global__ __launch_bounds__(256) void fc1_k(const float* __restrict__ flat,
                                             const float* __restrict__ W,
                                             float* __restrict__ z) {
    __shared__ float At[64][68];
    __shared__ float Wt[16][68];
    int tid = threadIdx.x;
    int r0 = blockIdx.x * 64;
    int j0 = blockIdx.y * 16;
    long k0 = (long)blockIdx.z * 4096;
    int r = tid & 63, jg = tid >> 6;
    float acc[4] = {0.f, 0.f, 0.f, 0.f};
    int ks = (tid & 15) * 4;
    int rw = tid >> 4;                        // 0..15

    for (int kc = 0; kc < 4096; kc += 64) {
#pragma unroll
        for (int p = 0; p < 4; p++) {
            int rr = rw + p * 16;
            float4 v = *(const float4*)&flat[(long)(r0 + rr) * 65536 + k0 + kc + ks];
            *(float4*)&At[rr][ks] = v;
        }
        float4 wv = *(const float4*)&W[(long)(j0 + rw) * 65536 + k0 + kc + ks];
        *(float4*)&Wt[rw][ks] = wv;
        __syncthreads();
#pragma unroll
        for (int k4 = 0; k4 < 16; k4++) {
            float4 a = *(const float4*)&At[r][k4 * 4];
#pragma unroll
            for (int jj = 0; jj < 4; jj++) {
                float4 w = *(const float4*)&Wt[jg * 4 + jj][k4 * 4];
                acc[jj] += a.x * w.x + a.y * w.y + a.z * w.z + a.w * w.w;
            }
        }
        __syncthreads();
    }
#pragma unroll
    for (int jj = 0; jj < 4; jj++)
        atomicAdd(&z[(r0 + r) * 128 + j0 + jg * 4 + jj], acc[jj]);
}

__global__ void zero_k(float* __restrict__ p, int n) {
    int i = blockIdx.x * 256 + threadIdx.x;
    if (i < n) p[i] = 0.f;
}

// ---------------- head: relu(z+b) @ fs_w + fs_b -> sigmoid*4+1; frame means ---------
__global__ __launch_bounds__(256) void head_k(const float* __restrict__ z,
                                              const float* __restrict__ b1,
                                              const float* __restrict__ fsw,
                                              const float* __restrict__ fsb,
                                              float* __restrict__ out) {
    __shared__ float sf[256];
    int r = threadIdx.x;
    float acc = fsb[0];
#pragma unroll
    for (int j4 = 0; j4 < 32; j4++) {
        float4 zv = *(const float4*)&z[r * 128 + j4 * 4];
        float4 bv = *(const float4*)&b1[j4 * 4];
        float4 wv = *(const float4*)&fsw[j4 * 4];
        acc += fmaxf(zv.x + bv.x, 0.f) * wv.x;
        acc += fmaxf(zv.y + bv.y, 0.f) * wv.y;
        acc += fmaxf(zv.z + bv.z, 0.f) * wv.z;
        acc += fmaxf(zv.w + bv.w, 0.f) * wv.w;
    }
    float val = sigmoidf_(acc) * 4.f + 1.f;
    out[16 + r] = val;                 // frames
    sf[r] = val;
    __syncthreads();
    if (r < 16) {
        float m = 0.f;
#pragma unroll
        for (int f = 0; f < 16; f++) m += sf[r * 16 + f];
        out[r] = m * (1.f / 16.f);     // utt
    }
}

extern "C" void kernel_launch(void* const* d_in, const int* in_sizes, int n_in,
                              void* d_out, int out_size, void* d_ws, size_t ws_size,
                              hipStream_t stream) {
    const float* audio = (const float*)d_in[0];
    const float* w0 = (const float*)d_in[2];
    const float* b0 = (const float*)d_in[3];
    const float* w1 = (const float*)d_in[4];
    const float* b1 = (const float*)d_in[5];
    const float* w2 = (const float*)d_in[6];
    const float* b2 = (const float*)d_in[7];
    const float* w3 = (const float*)d_in[8];
    const float* b3 = (const float*)d_in[9];
    const float* Wih_f = (const float*)d_in[10];
    const float* Whh_f = (const float*)d_in[11];
    const float* bih_f = (const float*)d_in[12];
    const float* bhh_f = (const float*)d_in[13];
    const float* Wih_b = (const float*)d_in[14];
    const float* Whh_b = (const float*)d_in[15];
    const float* bih_b = (const float*)d_in[16];
    const float* bhh_b = (const float*)d_in[17];
    const float* fc1_w = (const float*)d_in[18];
    const float* fc1_b = (const float*)d_in[19];
    const float* fs_w  = (const float*)d_in[20];
    const float* fs_b  = (const float*)d_in[21];
    float* out = (float*)d_out;

    char* ws = (char*)d_ws;
    // region A (0 .. 134.2MB): conv0 out, later Gf16+Gb16
    __half* Gf16 = (__half*)(ws);
    __half* Gb16 = (__half*)(ws + 67108864);
    float*  convA = (float*)(ws);
    // region B (134.2 .. 209.7MB): conv1 out, later X, later flat
    float* convB = (float*)(ws + 134217728);
    float* X     = convB;
    float* flat  = convB;
    // region C (209.7 .. 260.0MB): conv2 out, later z
    float* convC = (float*)(ws + 209715200);
    float* zbuf  = convC;
    // region D: transposed conv weights + packed Whh
    char* rd = ws + 260046848;
    float* w0t = (float*)(rd);
    float* w1t = (float*)(rd + 576);
    float* w2t = (float*)(rd + 19008);
    float* w3t = (float*)(rd + 92736);
    unsigned int* whhp = (unsigned int*)(rd + 387648);

    transpose_w<<<1, 256, 0, stream>>>(w0, w0t, 16, 1);
    transpose_w<<<18, 256, 0, stream>>>(w1, w1t, 32, 16);
    transpose_w<<<72, 256, 0, stream>>>(w2, w2t, 64, 32);
    transpose_w<<<288, 256, 0, stream>>>(w3, w3t, 128, 64);
    pack_whh<<<256, 256, 0, stream>>>(Whh_f, Whh_b, whhp);

    conv_k<1, 16, 81, 27, false><<<6912, 256, 0, stream>>>(audio, w0t, b0, convA);
    conv_k<16, 32, 27, 9, false><<<4608, 256, 0, stream>>>(convA, w1t, b1, convB);
    conv_k<32, 64, 9, 3, false><<<3072, 256, 0, stream>>>(convB, w2t, b2, convC);
    conv_k<64, 128, 3, 1, true><<<2048, 256, 0, stream>>>(convC, w3t, b3, X);

    gates_gemm<<<dim3(512, 8), 256, 0, stream>>>(X, Wih_f, Wih_b,
                                                 bih_f, bhh_f, bih_b, bhh_b,
                                                 Gf16, Gb16);

    lstm_k<<<512, 256, 0, stream>>>(Gf16, Gb16, whhp, flat);

    zero_k<<<128, 256, 0, stream>>>(zbuf, 256 * 128);
    fc1_k<<<dim3(4, 8, 16), 256, 0, stream>>>(flat, fc1_w, zbuf);
    head_k<<<1, 256, 0, stream>>>(zbuf, fc1_b, fs_w, fs_b, out);
}

// Round 2
// 870.546 us; speedup vs baseline: 2.6040x; 2.6040x over previous
//
#include <hip/hip_runtime.h>
#include <hip/hip_fp16.h>

#define BF 256
#define TSTEPS 256

typedef _Float16 h8_t __attribute__((ext_vector_type(8)));
typedef _Float16 h4_t __attribute__((ext_vector_type(4)));
typedef float f4_t __attribute__((ext_vector_type(4)));
typedef _Float16 h2v __attribute__((ext_vector_type(2)));

union H8 { uint4 u; h8_t v; };
union H4 { uint2 u; h4_t v; };

static __device__ __forceinline__ float fdot2f(unsigned int a, unsigned int b, float c) {
#if __has_builtin(__builtin_amdgcn_fdot2)
    union { unsigned int u; h2v v; } ca, cb;
    ca.u = a; cb.u = b;
    return __builtin_amdgcn_fdot2(ca.v, cb.v, c, false);
#else
    union { unsigned int u; __half2 h; } ca, cb;
    ca.u = a; cb.u = b;
    return c + __half2float(__low2half(ca.h)) * __half2float(__low2half(cb.h))
             + __half2float(__high2half(ca.h)) * __half2float(__high2half(cb.h));
#endif
}

static __device__ __forceinline__ float sigmoidf_(float x) {
    return 1.f / (1.f + __expf(-x));
}
static __device__ __forceinline__ float tanhf_(float x) {
    return 1.f - 2.f / (__expf(2.f * x) + 1.f);
}

// ---- w0 transpose: w[oc][0][kh][kw] -> wT[khw][oc] (fp32, tiny) --------------------
__global__ void transpose_w(const float* __restrict__ src, float* __restrict__ dst,
                            int OC, int IC) {
    int i = blockIdx.x * 256 + threadIdx.x;
    int n = OC * IC * 9;
    if (i >= n) return;
    int oc = i / (IC * 9);
    int rem = i % (IC * 9);
    dst[rem * OC + oc] = src[i];
}

// ---- generic f16 MFMA B-operand pack ----------------------------------------------
// dst[i] layout: chunk-major, i = ((chunk*4 + g)*OC + oc)*grp + j, grp = KS/4
// value = src[oc*oc_str + ic*ic_str + khw*k_str], ic = cc*KS + g*grp + j,
// chunk = khw*(IC/KS) + cc
__global__ void pack_wf16(const float* __restrict__ src, __half* __restrict__ dst,
                          int OC, int IC, int KS,
                          int oc_str, int ic_str, int k_str, int total) {
    int i = blockIdx.x * 256 + threadIdx.x;
    if (i >= total) return;
    int grp = KS / 4;
    int j = i % grp;
    int oc = (i / grp) % OC;
    int g = (i / (grp * OC)) & 3;
    int chunk = i / (grp * OC * 4);
    int CPK = IC / KS;
    int cc = chunk % CPK;
    int khw = chunk / CPK;
    int ic = cc * KS + g * grp + j;
    dst[i] = __float2half(src[oc * oc_str + ic * ic_str + khw * k_str]);
}

// ---- Whh f16 pack: P[dir][k2][col] ------------------------------------------------
__global__ void pack_whh(const float* __restrict__ Wf, const float* __restrict__ Wb,
                         unsigned int* __restrict__ P) {
    int i = blockIdx.x * 256 + threadIdx.x;
    if (i >= 2 * 64 * 512) return;
    int d = i / (64 * 512);
    int r = i % (64 * 512);
    int k2 = r / 512, col = r % 512;
    const float* W = d ? Wb : Wf;
    float a = W[col * 128 + k2 * 2];
    float b = W[col * 128 + k2 * 2 + 1];
    union { __half2 h; unsigned int u; } cv;
    cv.h = __floats2half2_rn(a, b);
    P[d * 64 * 512 + k2 * 512 + col] = cv.u;
}

// ---- conv0: 1->16 ch, VALU, NHWC f16 out ------------------------------------------
// in: audio fp32 [bf][256][81]; out: f16 [bf][256][27][16]
__global__ __launch_bounds__(256) void conv0_k(const float* __restrict__ in,
                                               const float* __restrict__ wT,
                                               const float* __restrict__ bias,
                                               __half* __restrict__ out) {
    __shared__ float wsm[9][16];
    __shared__ float bs[16];
    int tid = threadIdx.x;
    if (tid < 144) wsm[tid / 16][tid % 16] = wT[tid];
    if (tid < 16) bs[tid] = bias[tid];
    __syncthreads();
    int gid = blockIdx.x * 256 + tid;          // 256*256*27 total, exact
    int ow = gid % 27;
    int t = (gid / 27) % 256;
    int bf = gid / (27 * 256);
    float acc[16];
#pragma unroll
    for (int o = 0; o < 16; o++) acc[o] = bs[o];
    int iw0 = ow * 3 - 1;
#pragma unroll
    for (int kh = 0; kh < 3; kh++) {
        int tt = t + kh - 1;
        if ((unsigned)tt >= 256u) continue;
        const float* ip = in + ((long)bf * 256 + tt) * 81;
#pragma unroll
        for (int kw = 0; kw < 3; kw++) {
            int iw = iw0 + kw;
            if ((unsigned)iw >= 81u) continue;
            float x = ip[iw];
#pragma unroll
            for (int o = 0; o < 16; o++) acc[o] += x * wsm[kh * 3 + kw][o];
        }
    }
    __half2* op = (__half2*)(out + (long)gid * 16);
#pragma unroll
    for (int o = 0; o < 8; o++)
        op[o] = __floats2half2_rn(fmaxf(acc[2 * o], 0.f), fmaxf(acc[2 * o + 1], 0.f));
}

// ---- MFMA implicit-GEMM conv: NHWC f16 in/out -------------------------------------
// in: [bf][256][WIN][IC] f16. out: [bf][256][WOUT][OC] f16.
// M = spatial (bf*256+t)*WOUT+ow, N = OC, K = 9*IC in (kh,kw,ic) order.
template<int IC, int OC, int WIN, int WOUT, int KS>
__global__ __launch_bounds__(256) void convM_k(const __half* __restrict__ in,
                                               const __half* __restrict__ wp,
                                               const float* __restrict__ bias,
                                               __half* __restrict__ out) {
    constexpr int NT = OC / 16;
    constexpr int CPK = IC / KS;         // ic-chunks per (kh,kw)
    constexpr int NCHUNK = 9 * CPK;
    constexpr int GRP = KS / 4;          // halves per frag load
    int tid = threadIdx.x;
    int lane = tid & 63;
    int wv = tid >> 6;
    int l15 = lane & 15;
    int g = lane >> 4;
    int m = blockIdx.x * 64 + wv * 16 + l15;
    int ow = m % WOUT;
    int t = (m / WOUT) % 256;
    int bf = m / (WOUT * 256);

    f4_t acc[NT];
#pragma unroll
    for (int nt = 0; nt < NT; nt++)
#pragma unroll
        for (int r = 0; r < 4; r++) acc[nt][r] = 0.f;

#pragma unroll
    for (int chunk = 0; chunk < NCHUNK; chunk++) {
        int khw = chunk / CPK, cc = chunk % CPK;
        int kh = khw / 3;
        int kw = khw - kh * 3;
        int tt = t + kh - 1;
        int iw = ow * 3 + kw - 1;
        bool ok = ((unsigned)tt < 256u) && ((unsigned)iw < (unsigned)WIN);
        long aoff = ok ? (((long)(bf * 256 + tt) * WIN + iw) * IC + cc * KS + g * GRP) : 0;
        if constexpr (KS == 32) {
            H8 af;
            af.u = *(const uint4*)(in + aoff);
            if (!ok) af.u = make_uint4(0u, 0u, 0u, 0u);
#pragma unroll
            for (int nt = 0; nt < NT; nt++) {
                H8 bf8;
                bf8.u = *(const uint4*)(wp + ((long)(chunk * 4 + g) * OC + nt * 16 + l15) * GRP);
                acc[nt] = __builtin_amdgcn_mfma_f32_16x16x32_f16(af.v, bf8.v, acc[nt], 0, 0, 0);
            }
        } else {
            H4 af;
            af.u = *(const uint2*)(in + aoff);
            if (!ok) af.u = make_uint2(0u, 0u);
#pragma unroll
            for (int nt = 0; nt < NT; nt++) {
                H4 bf4;
                bf4.u = *(const uint2*)(wp + ((long)(chunk * 4 + g) * OC + nt * 16 + l15) * GRP);
                acc[nt] = __builtin_amdgcn_mfma_f32_16x16x16f16(af.v, bf4.v, acc[nt], 0, 0, 0);
            }
        }
    }
    // D: row = quad*4+r, col = lane&15
    int orow = blockIdx.x * 64 + wv * 16 + g * 4;
#pragma unroll
    for (int nt = 0; nt < NT; nt++) {
        int oc = nt * 16 + l15;
        float b = bias[oc];
#pragma unroll
        for (int r = 0; r < 4; r++) {
            float v = fmaxf(acc[nt][r] + b, 0.f);
            out[(long)(orow + r) * OC + oc] = __float2half(v);
        }
    }
}

// ---- gates MFMA GEMM: G[row][512] = X[row][128] @ Wih^T + (bih+bhh), f16 out ------
// block: M=128 (4 waves x 32), N=128 (8 ntiles); grid (512, 4); launched per dir
__global__ __launch_bounds__(256) void gates_k(const __half* __restrict__ X,
                                               const __half* __restrict__ wp,
                                               const float* __restrict__ b1,
                                               const float* __restrict__ b2,
                                               __half* __restrict__ G) {
    int tid = threadIdx.x;
    int lane = tid & 63;
    int wv = tid >> 6;
    int l15 = lane & 15;
    int g = lane >> 4;
    long r0 = (long)blockIdx.x * 128 + wv * 32;
    int n0 = blockIdx.y * 128;

    f4_t acc[2][8];
#pragma unroll
    for (int s = 0; s < 2; s++)
#pragma unroll
        for (int nt = 0; nt < 8; nt++)
#pragma unroll
            for (int r = 0; r < 4; r++) acc[s][nt][r] = 0.f;

#pragma unroll
    for (int chunk = 0; chunk < 4; chunk++) {
        H8 a0, a1;
        a0.u = *(const uint4*)(X + (r0 + l15) * 128 + chunk * 32 + g * 8);
        a1.u = *(const uint4*)(X + (r0 + 16 + l15) * 128 + chunk * 32 + g * 8);
#pragma unroll
        for (int nt = 0; nt < 8; nt++) {
            H8 bw;
            bw.u = *(const uint4*)(wp + ((long)(chunk * 4 + g) * 512 + n0 + nt * 16 + l15) * 8);
            acc[0][nt] = __builtin_amdgcn_mfma_f32_16x16x32_f16(a0.v, bw.v, acc[0][nt], 0, 0, 0);
            acc[1][nt] = __builtin_amdgcn_mfma_f32_16x16x32_f16(a1.v, bw.v, acc[1][nt], 0, 0, 0);
        }
    }
#pragma unroll
    for (int nt = 0; nt < 8; nt++) {
        int col = n0 + nt * 16 + l15;
        float bias = b1[col] + b2[col];
#pragma unroll
        for (int s = 0; s < 2; s++) {
            long row = r0 + s * 16 + g * 4;
#pragma unroll
            for (int r = 0; r < 4; r++)
                G[(row + r) * 512 + col] = __float2half(acc[s][nt][r] + bias);
        }
    }
}

// ---- LSTM recurrence: 1 block per (dir, chain) ------------------------------------
__global__ __launch_bounds__(256) void lstm_k(const __half* __restrict__ Gf,
                                              const __half* __restrict__ Gb,
                                              const unsigned int* __restrict__ WhhP,
                                              float* __restrict__ flat) {
    int bid = blockIdx.x;
    int b = bid & 255;
    int dir = bid >> 8;
    const __half* G = dir ? Gb : Gf;
    const unsigned int* WP = WhhP + dir * (64 * 512);
    int tid = threadIdx.x;
    int c0 = tid, c1 = tid + 256;

    unsigned int w0[64], w1[64];
#pragma unroll
    for (int i = 0; i < 64; i++) { w0[i] = WP[i * 512 + c0]; w1[i] = WP[i * 512 + c1]; }

    __shared__ uint4 h4s[16];
    __shared__ float zl[512];
    float cst = 0.f;
    if (tid < 16) h4s[tid] = make_uint4(0u, 0u, 0u, 0u);
    __syncthreads();

    for (int t = 0; t < 256; t++) {
        int ts = dir ? (255 - t) : t;
        long row = ((long)b * 256 + ts) * 512;     // rows are bf*256+t now
        float z0 = __half2float(G[row + c0]);
        float z1 = __half2float(G[row + c1]);
#pragma unroll
        for (int i4 = 0; i4 < 16; i4++) {
            uint4 hp = h4s[i4];
            z0 = fdot2f(hp.x, w0[i4 * 4 + 0], z0);
            z0 = fdot2f(hp.y, w0[i4 * 4 + 1], z0);
            z0 = fdot2f(hp.z, w0[i4 * 4 + 2], z0);
            z0 = fdot2f(hp.w, w0[i4 * 4 + 3], z0);
            z1 = fdot2f(hp.x, w1[i4 * 4 + 0], z1);
            z1 = fdot2f(hp.y, w1[i4 * 4 + 1], z1);
            z1 = fdot2f(hp.z, w1[i4 * 4 + 2], z1);
            z1 = fdot2f(hp.w, w1[i4 * 4 + 3], z1);
        }
        zl[c0] = z0; zl[c1] = z1;
        __syncthreads();
        if (tid < 128) {
            float ig = sigmoidf_(zl[tid]);
            float fg = sigmoidf_(zl[128 + tid]);
            float gg = tanhf_(zl[256 + tid]);
            float og = sigmoidf_(zl[384 + tid]);
            cst = fg * cst + ig * gg;
            float h = og * tanhf_(cst);
            ((__half*)h4s)[tid] = __float2half(h);
            flat[(long)b * 65536 + ts * 256 + dir * 128 + tid] = h;
        }
        __syncthreads();
    }
}

// ---- FC1 split-K fp32 -------------------------------------------------------------
__global__ __launch_bounds__(256) void fc1_k(const float* __restrict__ flat,
                                             const float* __restrict__ W,
                                             float* __restrict__ z) {
    __shared__ float At[64][68];
    __shared__ float Wt[16][68];
    int tid = threadIdx.x;
    int r0 = blockIdx.x * 64;
    int j0 = blockIdx.y * 16;
    long k0 = (long)blockIdx.z * 4096;
    int r = tid & 63, jg = tid >> 6;
    float acc[4] = {0.f, 0.f, 0.f, 0.f};
    int ks = (tid & 15) * 4;
    int rw = tid >> 4;

    for (int kc = 0; kc < 4096; kc += 64) {
#pragma unroll
        for (int p = 0; p < 4; p++) {
            int rr = rw + p * 16;
            float4 v = *(const float4*)&flat[(long)(r0 + rr) * 65536 + k0 + kc + ks];
            *(float4*)&At[rr][ks] = v;
        }
        float4 wv = *(const float4*)&W[(long)(j0 + rw) * 65536 + k0 + kc + ks];
        *(float4*)&Wt[rw][ks] = wv;
        __syncthreads();
#pragma unroll
        for (int k4 = 0; k4 < 16; k4++) {
            float4 a = *(const float4*)&At[r][k4 * 4];
#pragma unroll
            for (int jj = 0; jj < 4; jj++) {
                float4 w = *(const float4*)&Wt[jg * 4 + jj][k4 * 4];
                acc[jj] += a.x * w.x + a.y * w.y + a.z * w.z + a.w * w.w;
            }
        }
        __syncthreads();
    }
#pragma unroll
    for (int jj = 0; jj < 4; jj++)
        atomicAdd(&z[(r0 + r) * 128 + j0 + jg * 4 + jj], acc[jj]);
}

__global__ void zero_k(float* __restrict__ p, int n) {
    int i = blockIdx.x * 256 + threadIdx.x;
    if (i < n) p[i] = 0.f;
}

// ---- head -------------------------------------------------------------------------
__global__ __launch_bounds__(256) void head_k(const float* __restrict__ z,
                                              const float* __restrict__ b1,
                                              const float* __restrict__ fsw,
                                              const float* __restrict__ fsb,
                                              float* __restrict__ out) {
    __shared__ float sf[256];
    int r = threadIdx.x;
    float acc = fsb[0];
#pragma unroll
    for (int j4 = 0; j4 < 32; j4++) {
        float4 zv = *(const float4*)&z[r * 128 + j4 * 4];
        float4 bv = *(const float4*)&b1[j4 * 4];
        float4 wv = *(const float4*)&fsw[j4 * 4];
        acc += fmaxf(zv.x + bv.x, 0.f) * wv.x;
        acc += fmaxf(zv.y + bv.y, 0.f) * wv.y;
        acc += fmaxf(zv.z + bv.z, 0.f) * wv.z;
        acc += fmaxf(zv.w + bv.w, 0.f) * wv.w;
    }
    float val = sigmoidf_(acc) * 4.f + 1.f;
    out[16 + r] = val;
    sf[r] = val;
    __syncthreads();
    if (r < 16) {
        float m = 0.f;
#pragma unroll
        for (int f = 0; f < 16; f++) m += sf[r * 16 + f];
        out[r] = m * (1.f / 16.f);
    }
}

extern "C" void kernel_launch(void* const* d_in, const int* in_sizes, int n_in,
                              void* d_out, int out_size, void* d_ws, size_t ws_size,
                              hipStream_t stream) {
    const float* audio = (const float*)d_in[0];
    const float* w0 = (const float*)d_in[2];
    const float* b0 = (const float*)d_in[3];
    const float* w1 = (const float*)d_in[4];
    const float* b1 = (const float*)d_in[5];
    const float* w2 = (const float*)d_in[6];
    const float* b2 = (const float*)d_in[7];
    const float* w3 = (const float*)d_in[8];
    const float* b3 = (const float*)d_in[9];
    const float* Wih_f = (const float*)d_in[10];
    const float* Whh_f = (const float*)d_in[11];
    const float* bih_f = (const float*)d_in[12];
    const float* bhh_f = (const float*)d_in[13];
    const float* Wih_b = (const float*)d_in[14];
    const float* Whh_b = (const float*)d_in[15];
    const float* bih_b = (const float*)d_in[16];
    const float* bhh_b = (const float*)d_in[17];
    const float* fc1_w = (const float*)d_in[18];
    const float* fc1_b = (const float*)d_in[19];
    const float* fs_w = (const float*)d_in[20];
    const float* fs_b = (const float*)d_in[21];
    float* out = (float*)d_out;

    char* ws = (char*)d_ws;
    // lifetimes: out1 dies before Gf written; out0 dies before flat written
    __half* Gf   = (__half*)(ws);                    // 67.1 MB
    __half* out1 = (__half*)(ws);                    // 37.7 MB (before Gf)
    __half* Gb   = (__half*)(ws + 67108864);         // 67.1 MB
    float*  flat = (float*)(ws + 134217728);         // 67.1 MB
    __half* out0 = (__half*)(ws + 134217728);        // 56.6 MB (before flat)
    __half* X    = (__half*)(ws + 201326592);        // 16.8 MB
    __half* out2 = (__half*)(ws + 218103808);        // 25.2 MB
    char* rd = ws + 243269632;
    float*  w0t  = (float*)(rd);
    __half* w1p  = (__half*)(rd + 1024);
    __half* w2p  = (__half*)(rd + 10240);
    __half* w3p  = (__half*)(rd + 47104);
    __half* wfp  = (__half*)(rd + 194560);
    __half* wbp  = (__half*)(rd + 325632);
    unsigned int* whhp = (unsigned int*)(rd + 456704);
    float*  zbuf = (float*)(rd + 718848);

    // weight prep
    transpose_w<<<1, 256, 0, stream>>>(w0, w0t, 16, 1);
    pack_wf16<<<18, 256, 0, stream>>>(w1, w1p, 32, 16, 16, 144, 9, 1, 4608);
    pack_wf16<<<72, 256, 0, stream>>>(w2, w2p, 64, 32, 32, 288, 9, 1, 18432);
    pack_wf16<<<288, 256, 0, stream>>>(w3, w3p, 128, 64, 32, 576, 9, 1, 73728);
    pack_wf16<<<256, 256, 0, stream>>>(Wih_f, wfp, 512, 128, 32, 128, 1, 0, 65536);
    pack_wf16<<<256, 256, 0, stream>>>(Wih_b, wbp, 512, 128, 32, 128, 1, 0, 65536);
    pack_whh<<<256, 256, 0, stream>>>(Whh_f, Whh_b, whhp);

    // conv chain (NHWC f16)
    conv0_k<<<6912, 256, 0, stream>>>(audio, w0t, b0, out0);
    convM_k<16, 32, 27, 9, 16><<<9216, 256, 0, stream>>>(out0, w1p, b1, out1);
    convM_k<32, 64, 9, 3, 32><<<3072, 256, 0, stream>>>(out1, w2p, b2, out2);
    convM_k<64, 128, 3, 1, 32><<<1024, 256, 0, stream>>>(out2, w3p, b3, X);

    // gates
    gates_k<<<dim3(512, 4), 256, 0, stream>>>(X, wfp, bih_f, bhh_f, Gf);
    gates_k<<<dim3(512, 4), 256, 0, stream>>>(X, wbp, bih_b, bhh_b, Gb);

    // recurrence
    lstm_k<<<512, 256, 0, stream>>>(Gf, Gb, whhp, flat);

    // FC head
    zero_k<<<128, 256, 0, stream>>>(zbuf, 256 * 128);
    fc1_k<<<dim3(4, 8, 16), 256, 0, stream>>>(flat, fc1_w, zbuf);
    head_k<<<1, 256, 0, stream>>>(zbuf, fc1_b, fs_w, fs_b, out);
}

// Round 3
// 690.872 us; speedup vs baseline: 3.2812x; 1.2601x over previous
//
#include <hip/hip_runtime.h>
#include <hip/hip_fp16.h>

#define BF 256
#define TSTEPS 256

typedef _Float16 h8_t __attribute__((ext_vector_type(8)));
typedef _Float16 h4_t __attribute__((ext_vector_type(4)));
typedef float f4_t __attribute__((ext_vector_type(4)));
typedef _Float16 h2v __attribute__((ext_vector_type(2)));

union H8 { uint4 u; h8_t v; };
union H4 { uint2 u; h4_t v; };

static __device__ __forceinline__ float fdot2f(unsigned int a, unsigned int b, float c) {
#if __has_builtin(__builtin_amdgcn_fdot2)
    union { unsigned int u; h2v v; } ca, cb;
    ca.u = a; cb.u = b;
    return __builtin_amdgcn_fdot2(ca.v, cb.v, c, false);
#else
    union { unsigned int u; __half2 h; } ca, cb;
    ca.u = a; cb.u = b;
    return c + __half2float(__low2half(ca.h)) * __half2float(__low2half(cb.h))
             + __half2float(__high2half(ca.h)) * __half2float(__high2half(cb.h));
#endif
}

static __device__ __forceinline__ float sigmoidf_(float x) {
    return 1.f / (1.f + __expf(-x));
}
static __device__ __forceinline__ float tanhf_(float x) {
    return 1.f - 2.f / (__expf(2.f * x) + 1.f);
}

// ---- w0 transpose: w[oc][0][kh][kw] -> wT[khw][oc] (fp32, tiny) --------------------
__global__ void transpose_w(const float* __restrict__ src, float* __restrict__ dst,
                            int OC, int IC) {
    int i = blockIdx.x * 256 + threadIdx.x;
    int n = OC * IC * 9;
    if (i >= n) return;
    int oc = i / (IC * 9);
    int rem = i % (IC * 9);
    dst[rem * OC + oc] = src[i];
}

// ---- generic f16 MFMA B-operand pack ----------------------------------------------
// dst[i]: i = ((chunk*4 + g)*OC + oc)*grp + j, grp = KS/4
// value = src[oc*oc_str + ic*ic_str + khw*k_str], ic = cc*KS + g*grp + j,
// chunk = khw*(IC/KS) + cc
__global__ void pack_wf16(const float* __restrict__ src, __half* __restrict__ dst,
                          int OC, int IC, int KS,
                          int oc_str, int ic_str, int k_str, int total) {
    int i = blockIdx.x * 256 + threadIdx.x;
    if (i >= total) return;
    int grp = KS / 4;
    int j = i % grp;
    int oc = (i / grp) % OC;
    int g = (i / (grp * OC)) & 3;
    int chunk = i / (grp * OC * 4);
    int CPK = IC / KS;
    int cc = chunk % CPK;
    int khw = chunk / CPK;
    int ic = cc * KS + g * grp + j;
    dst[i] = __float2half(src[(long)oc * oc_str + (long)ic * ic_str + khw * k_str]);
}

// ---- Whh f16 pack: P[dir][k2][col] ------------------------------------------------
__global__ void pack_whh(const float* __restrict__ Wf, const float* __restrict__ Wb,
                         unsigned int* __restrict__ P) {
    int i = blockIdx.x * 256 + threadIdx.x;
    if (i >= 2 * 64 * 512) return;
    int d = i / (64 * 512);
    int r = i % (64 * 512);
    int k2 = r / 512, col = r % 512;
    const float* W = d ? Wb : Wf;
    float a = W[col * 128 + k2 * 2];
    float b = W[col * 128 + k2 * 2 + 1];
    union { __half2 h; unsigned int u; } cv;
    cv.h = __floats2half2_rn(a, b);
    P[d * 64 * 512 + k2 * 512 + col] = cv.u;
}

// ---- conv0: 1->16 ch, VALU, NHWC f16 out ------------------------------------------
__global__ __launch_bounds__(256) void conv0_k(const float* __restrict__ in,
                                               const float* __restrict__ wT,
                                               const float* __restrict__ bias,
                                               __half* __restrict__ out) {
    __shared__ float wsm[9][16];
    __shared__ float bs[16];
    int tid = threadIdx.x;
    if (tid < 144) wsm[tid / 16][tid % 16] = wT[tid];
    if (tid < 16) bs[tid] = bias[tid];
    __syncthreads();
    int gid = blockIdx.x * 256 + tid;
    int ow = gid % 27;
    int t = (gid / 27) % 256;
    int bf = gid / (27 * 256);
    float acc[16];
#pragma unroll
    for (int o = 0; o < 16; o++) acc[o] = bs[o];
    int iw0 = ow * 3 - 1;
#pragma unroll
    for (int kh = 0; kh < 3; kh++) {
        int tt = t + kh - 1;
        if ((unsigned)tt >= 256u) continue;
        const float* ip = in + ((long)bf * 256 + tt) * 81;
#pragma unroll
        for (int kw = 0; kw < 3; kw++) {
            int iw = iw0 + kw;
            if ((unsigned)iw >= 81u) continue;
            float x = ip[iw];
#pragma unroll
            for (int o = 0; o < 16; o++) acc[o] += x * wsm[kh * 3 + kw][o];
        }
    }
    __half2* op = (__half2*)(out + (long)gid * 16);
#pragma unroll
    for (int o = 0; o < 8; o++)
        op[o] = __floats2half2_rn(fmaxf(acc[2 * o], 0.f), fmaxf(acc[2 * o + 1], 0.f));
}

// ---- MFMA implicit-GEMM conv: NHWC f16 in/out -------------------------------------
template<int IC, int OC, int WIN, int WOUT, int KS>
__global__ __launch_bounds__(256) void convM_k(const __half* __restrict__ in,
                                               const __half* __restrict__ wp,
                                               const float* __restrict__ bias,
                                               __half* __restrict__ out) {
    constexpr int NT = OC / 16;
    constexpr int CPK = IC / KS;
    constexpr int NCHUNK = 9 * CPK;
    constexpr int GRP = KS / 4;
    int tid = threadIdx.x;
    int lane = tid & 63;
    int wv = tid >> 6;
    int l15 = lane & 15;
    int g = lane >> 4;
    int m = blockIdx.x * 64 + wv * 16 + l15;
    int ow = m % WOUT;
    int t = (m / WOUT) % 256;
    int bf = m / (WOUT * 256);

    f4_t acc[NT];
#pragma unroll
    for (int nt = 0; nt < NT; nt++)
#pragma unroll
        for (int r = 0; r < 4; r++) acc[nt][r] = 0.f;

#pragma unroll
    for (int chunk = 0; chunk < NCHUNK; chunk++) {
        int khw = chunk / CPK, cc = chunk % CPK;
        int kh = khw / 3;
        int kw = khw - kh * 3;
        int tt = t + kh - 1;
        int iw = ow * 3 + kw - 1;
        bool ok = ((unsigned)tt < 256u) && ((unsigned)iw < (unsigned)WIN);
        long aoff = ok ? (((long)(bf * 256 + tt) * WIN + iw) * IC + cc * KS + g * GRP) : 0;
        if constexpr (KS == 32) {
            H8 af;
            af.u = *(const uint4*)(in + aoff);
            if (!ok) af.u = make_uint4(0u, 0u, 0u, 0u);
#pragma unroll
            for (int nt = 0; nt < NT; nt++) {
                H8 bf8;
                bf8.u = *(const uint4*)(wp + ((long)(chunk * 4 + g) * OC + nt * 16 + l15) * GRP);
                acc[nt] = __builtin_amdgcn_mfma_f32_16x16x32_f16(af.v, bf8.v, acc[nt], 0, 0, 0);
            }
        } else {
            H4 af;
            af.u = *(const uint2*)(in + aoff);
            if (!ok) af.u = make_uint2(0u, 0u);
#pragma unroll
            for (int nt = 0; nt < NT; nt++) {
                H4 bf4;
                bf4.u = *(const uint2*)(wp + ((long)(chunk * 4 + g) * OC + nt * 16 + l15) * GRP);
                acc[nt] = __builtin_amdgcn_mfma_f32_16x16x16f16(af.v, bf4.v, acc[nt], 0, 0, 0);
            }
        }
    }
    int orow = blockIdx.x * 64 + wv * 16 + g * 4;
#pragma unroll
    for (int nt = 0; nt < NT; nt++) {
        int oc = nt * 16 + l15;
        float b = bias[oc];
#pragma unroll
        for (int r = 0; r < 4; r++) {
            float v = fmaxf(acc[nt][r] + b, 0.f);
            out[(long)(orow + r) * OC + oc] = __float2half(v);
        }
    }
}

// ---- gates MFMA GEMM: G[row][512] = X[row][128] @ Wih^T + (bih+bhh), f16 out ------
__global__ __launch_bounds__(256) void gates_k(const __half* __restrict__ X,
                                               const __half* __restrict__ wp,
                                               const float* __restrict__ b1,
                                               const float* __restrict__ b2,
                                               __half* __restrict__ G) {
    int tid = threadIdx.x;
    int lane = tid & 63;
    int wv = tid >> 6;
    int l15 = lane & 15;
    int g = lane >> 4;
    long r0 = (long)blockIdx.x * 128 + wv * 32;
    int n0 = blockIdx.y * 128;

    f4_t acc[2][8];
#pragma unroll
    for (int s = 0; s < 2; s++)
#pragma unroll
        for (int nt = 0; nt < 8; nt++)
#pragma unroll
            for (int r = 0; r < 4; r++) acc[s][nt][r] = 0.f;

#pragma unroll
    for (int chunk = 0; chunk < 4; chunk++) {
        H8 a0, a1;
        a0.u = *(const uint4*)(X + (r0 + l15) * 128 + chunk * 32 + g * 8);
        a1.u = *(const uint4*)(X + (r0 + 16 + l15) * 128 + chunk * 32 + g * 8);
#pragma unroll
        for (int nt = 0; nt < 8; nt++) {
            H8 bw;
            bw.u = *(const uint4*)(wp + ((long)(chunk * 4 + g) * 512 + n0 + nt * 16 + l15) * 8);
            acc[0][nt] = __builtin_amdgcn_mfma_f32_16x16x32_f16(a0.v, bw.v, acc[0][nt], 0, 0, 0);
            acc[1][nt] = __builtin_amdgcn_mfma_f32_16x16x32_f16(a1.v, bw.v, acc[1][nt], 0, 0, 0);
        }
    }
#pragma unroll
    for (int nt = 0; nt < 8; nt++) {
        int col = n0 + nt * 16 + l15;
        float bias = b1[col] + b2[col];
#pragma unroll
        for (int s = 0; s < 2; s++) {
            long row = r0 + s * 16 + g * 4;
#pragma unroll
            for (int r = 0; r < 4; r++)
                G[(row + r) * 512 + col] = __float2half(acc[s][nt][r] + bias);
        }
    }
}

// ---- LSTM recurrence: 1 block per (dir, chain); G prefetch + 4-way accum split ----
__global__ __launch_bounds__(256) void lstm_k(const __half* __restrict__ Gf,
                                              const __half* __restrict__ Gb,
                                              const unsigned int* __restrict__ WhhP,
                                              __half* __restrict__ flat) {
    int bid = blockIdx.x;
    int b = bid & 255;
    int dir = bid >> 8;
    const __half* G = dir ? Gb : Gf;
    const unsigned int* WP = WhhP + dir * (64 * 512);
    int tid = threadIdx.x;
    int c0 = tid, c1 = tid + 256;

    unsigned int w0[64], w1[64];
#pragma unroll
    for (int i = 0; i < 64; i++) { w0[i] = WP[i * 512 + c0]; w1[i] = WP[i * 512 + c1]; }

    __shared__ uint4 h4s[16];
    __shared__ float zl[512];
    float cst = 0.f;
    if (tid < 16) h4s[tid] = make_uint4(0u, 0u, 0u, 0u);
    __syncthreads();

    // preload t=0's gate pre-activations
    int ts0 = dir ? 255 : 0;
    __half g0 = G[((long)b * 256 + ts0) * 512 + c0];
    __half g1 = G[((long)b * 256 + ts0) * 512 + c1];

    for (int t = 0; t < 256; t++) {
        int ts = dir ? (255 - t) : t;
        int tn = (t == 255) ? ts : (dir ? ts - 1 : ts + 1);
        long rown = ((long)b * 256 + tn) * 512;
        __half ng0 = G[rown + c0];     // prefetch next step (hidden under dots)
        __half ng1 = G[rown + c1];

        float a0[4] = {__half2float(g0), 0.f, 0.f, 0.f};
        float a1[4] = {__half2float(g1), 0.f, 0.f, 0.f};
#pragma unroll
        for (int i4 = 0; i4 < 16; i4++) {
            uint4 hp = h4s[i4];
            int s = i4 & 3;
            a0[s] = fdot2f(hp.x, w0[i4 * 4 + 0], a0[s]);
            a0[s] = fdot2f(hp.y, w0[i4 * 4 + 1], a0[s]);
            a0[s] = fdot2f(hp.z, w0[i4 * 4 + 2], a0[s]);
            a0[s] = fdot2f(hp.w, w0[i4 * 4 + 3], a0[s]);
            a1[s] = fdot2f(hp.x, w1[i4 * 4 + 0], a1[s]);
            a1[s] = fdot2f(hp.y, w1[i4 * 4 + 1], a1[s]);
            a1[s] = fdot2f(hp.z, w1[i4 * 4 + 2], a1[s]);
            a1[s] = fdot2f(hp.w, w1[i4 * 4 + 3], a1[s]);
        }
        zl[c0] = (a0[0] + a0[1]) + (a0[2] + a0[3]);
        zl[c1] = (a1[0] + a1[1]) + (a1[2] + a1[3]);
        __syncthreads();
        if (tid < 128) {
            float ig = sigmoidf_(zl[tid]);
            float fg = sigmoidf_(zl[128 + tid]);
            float gg = tanhf_(zl[256 + tid]);
            float og = sigmoidf_(zl[384 + tid]);
            cst = fg * cst + ig * gg;
            float h = og * tanhf_(cst);
            __half hh = __float2half(h);
            ((__half*)h4s)[tid] = hh;
            flat[(long)b * 65536 + ts * 256 + dir * 128 + tid] = hh;
        }
        __syncthreads();
        g0 = ng0; g1 = ng1;
    }
}

// ---- FC1 MFMA split-K: z[256][128] += flat16 @ fc1_w16^T --------------------------
// grid (4, 64): blockIdx.x = m-block of 64 rows, blockIdx.y = K-slice of 1024
__global__ __launch_bounds__(256) void fc1m_k(const __half* __restrict__ flat,
                                              const __half* __restrict__ wp,
                                              float* __restrict__ z) {
    int tid = threadIdx.x;
    int lane = tid & 63;
    int wv = tid >> 6;
    int l15 = lane & 15;
    int g = lane >> 4;
    int m0 = blockIdx.x * 64 + wv * 16;
    long k0 = (long)blockIdx.y * 1024;

    f4_t acc[8];
#pragma unroll
    for (int nt = 0; nt < 8; nt++)
#pragma unroll
        for (int r = 0; r < 4; r++) acc[nt][r] = 0.f;

    for (int c = 0; c < 32; c++) {
        long chunk = (k0 >> 5) + c;
        H8 af;
        af.u = *(const uint4*)(flat + (long)(m0 + l15) * 65536 + k0 + c * 32 + g * 8);
#pragma unroll
        for (int nt = 0; nt < 8; nt++) {
            H8 bw;
            bw.u = *(const uint4*)(wp + ((chunk * 4 + g) * 128 + nt * 16 + l15) * 8);
            acc[nt] = __builtin_amdgcn_mfma_f32_16x16x32_f16(af.v, bw.v, acc[nt], 0, 0, 0);
        }
    }
#pragma unroll
    for (int nt = 0; nt < 8; nt++)
#pragma unroll
        for (int r = 0; r < 4; r++)
            atomicAdd(&z[(m0 + g * 4 + r) * 128 + nt * 16 + l15], acc[nt][r]);
}

__global__ void zero_k(float* __restrict__ p, int n) {
    int i = blockIdx.x * 256 + threadIdx.x;
    if (i < n) p[i] = 0.f;
}

// ---- head -------------------------------------------------------------------------
__global__ __launch_bounds__(256) void head_k(const float* __restrict__ z,
                                              const float* __restrict__ b1,
                                              const float* __restrict__ fsw,
                                              const float* __restrict__ fsb,
                                              float* __restrict__ out) {
    __shared__ float sf[256];
    int r = threadIdx.x;
    float acc = fsb[0];
#pragma unroll
    for (int j4 = 0; j4 < 32; j4++) {
        float4 zv = *(const float4*)&z[r * 128 + j4 * 4];
        float4 bv = *(const float4*)&b1[j4 * 4];
        float4 wv = *(const float4*)&fsw[j4 * 4];
        acc += fmaxf(zv.x + bv.x, 0.f) * wv.x;
        acc += fmaxf(zv.y + bv.y, 0.f) * wv.y;
        acc += fmaxf(zv.z + bv.z, 0.f) * wv.z;
        acc += fmaxf(zv.w + bv.w, 0.f) * wv.w;
    }
    float val = sigmoidf_(acc) * 4.f + 1.f;
    out[16 + r] = val;
    sf[r] = val;
    __syncthreads();
    if (r < 16) {
        float m = 0.f;
#pragma unroll
        for (int f = 0; f < 16; f++) m += sf[r * 16 + f];
        out[r] = m * (1.f / 16.f);
    }
}

extern "C" void kernel_launch(void* const* d_in, const int* in_sizes, int n_in,
                              void* d_out, int out_size, void* d_ws, size_t ws_size,
                              hipStream_t stream) {
    const float* audio = (const float*)d_in[0];
    const float* w0 = (const float*)d_in[2];
    const float* b0 = (const float*)d_in[3];
    const float* w1 = (const float*)d_in[4];
    const float* b1 = (const float*)d_in[5];
    const float* w2 = (const float*)d_in[6];
    const float* b2 = (const float*)d_in[7];
    const float* w3 = (const float*)d_in[8];
    const float* b3 = (const float*)d_in[9];
    const float* Wih_f = (const float*)d_in[10];
    const float* Whh_f = (const float*)d_in[11];
    const float* bih_f = (const float*)d_in[12];
    const float* bhh_f = (const float*)d_in[13];
    const float* Wih_b = (const float*)d_in[14];
    const float* Whh_b = (const float*)d_in[15];
    const float* bih_b = (const float*)d_in[16];
    const float* bhh_b = (const float*)d_in[17];
    const float* fc1_w = (const float*)d_in[18];
    const float* fc1_b = (const float*)d_in[19];
    const float* fs_w = (const float*)d_in[20];
    const float* fs_b = (const float*)d_in[21];
    float* out = (float*)d_out;

    char* ws = (char*)d_ws;
    // lifetimes: out1 dies before Gf; out0 dies before flat16; Gf/Gb die before fc1p
    __half* Gf    = (__half*)(ws);                    // 67.1 MB
    __half* out1  = (__half*)(ws);                    // 37.7 MB (pre-Gf)
    __half* fc1p  = (__half*)(ws);                    // 16.8 MB (post-lstm, in Gf)
    __half* Gb    = (__half*)(ws + 67108864);         // 67.1 MB
    __half* flat16= (__half*)(ws + 134217728);        // 33.6 MB
    __half* out0  = (__half*)(ws + 134217728);        // 56.6 MB (pre-flat16)
    __half* X     = (__half*)(ws + 201326592);        // 16.8 MB
    __half* out2  = (__half*)(ws + 218103808);        // 25.2 MB
    char* rd = ws + 243269632;
    float*  w0t  = (float*)(rd);
    __half* w1p  = (__half*)(rd + 1024);
    __half* w2p  = (__half*)(rd + 10240);
    __half* w3p  = (__half*)(rd + 47104);
    __half* wfp  = (__half*)(rd + 194560);
    __half* wbp  = (__half*)(rd + 325632);
    unsigned int* whhp = (unsigned int*)(rd + 456704);
    float*  zbuf = (float*)(rd + 718848);

    // weight prep
    transpose_w<<<1, 256, 0, stream>>>(w0, w0t, 16, 1);
    pack_wf16<<<18, 256, 0, stream>>>(w1, w1p, 32, 16, 16, 144, 9, 1, 4608);
    pack_wf16<<<72, 256, 0, stream>>>(w2, w2p, 64, 32, 32, 288, 9, 1, 18432);
    pack_wf16<<<288, 256, 0, stream>>>(w3, w3p, 128, 64, 32, 576, 9, 1, 73728);
    pack_wf16<<<256, 256, 0, stream>>>(Wih_f, wfp, 512, 128, 32, 128, 1, 0, 65536);
    pack_wf16<<<256, 256, 0, stream>>>(Wih_b, wbp, 512, 128, 32, 128, 1, 0, 65536);
    pack_whh<<<256, 256, 0, stream>>>(Whh_f, Whh_b, whhp);

    // conv chain (NHWC f16)
    conv0_k<<<6912, 256, 0, stream>>>(audio, w0t, b0, out0);
    convM_k<16, 32, 27, 9, 16><<<9216, 256, 0, stream>>>(out0, w1p, b1, out1);
    convM_k<32, 64, 9, 3, 32><<<3072, 256, 0, stream>>>(out1, w2p, b2, out2);
    convM_k<64, 128, 3, 1, 32><<<1024, 256, 0, stream>>>(out2, w3p, b3, X);

    // gates
    gates_k<<<dim3(512, 4), 256, 0, stream>>>(X, wfp, bih_f, bhh_f, Gf);
    gates_k<<<dim3(512, 4), 256, 0, stream>>>(X, wbp, bih_b, bhh_b, Gb);

    // recurrence (writes f16 flat)
    lstm_k<<<512, 256, 0, stream>>>(Gf, Gb, whhp, flat16);

    // FC head: pack fc1_w (into dead Gf region), split-K MFMA, head
    pack_wf16<<<32768, 256, 0, stream>>>(fc1_w, fc1p, 128, 65536, 32, 65536, 1, 0, 8388608);
    zero_k<<<128, 256, 0, stream>>>(zbuf, 256 * 128);
    fc1m_k<<<dim3(4, 64), 256, 0, stream>>>(flat16, fc1p, zbuf);
    head_k<<<1, 256, 0, stream>>>(zbuf, fc1_b, fs_w, fs_b, out);
}

// Round 4
// 662.772 us; speedup vs baseline: 3.4204x; 1.0424x over previous
//
#include <hip/hip_runtime.h>
#include <hip/hip_fp16.h>

#define BF 256
#define TSTEPS 256

typedef _Float16 h8_t __attribute__((ext_vector_type(8)));
typedef _Float16 h4_t __attribute__((ext_vector_type(4)));
typedef float f4_t __attribute__((ext_vector_type(4)));

union H8 { uint4 u; h8_t v; };
union H4 { uint2 u; h4_t v; };

static __device__ __forceinline__ float sigmoidf_(float x) {
    return 1.f / (1.f + __expf(-x));
}
static __device__ __forceinline__ float tanhf_(float x) {
    return 1.f - 2.f / (__expf(2.f * x) + 1.f);
}

// ---- w0 transpose: w[oc][0][kh][kw] -> wT[khw][oc] (fp32, tiny) --------------------
__global__ void transpose_w(const float* __restrict__ src, float* __restrict__ dst,
                            int OC, int IC) {
    int i = blockIdx.x * 256 + threadIdx.x;
    int n = OC * IC * 9;
    if (i >= n) return;
    int oc = i / (IC * 9);
    int rem = i % (IC * 9);
    dst[rem * OC + oc] = src[i];
}

// ---- generic f16 MFMA operand pack ------------------------------------------------
// dst[i]: i = ((chunk*4 + g)*OC + oc)*grp + j, grp = KS/4
// value = src[oc*oc_str + ic*ic_str + khw*k_str], ic = cc*KS + g*grp + j,
// chunk = khw*(IC/KS) + cc
__global__ void pack_wf16(const float* __restrict__ src, __half* __restrict__ dst,
                          int OC, int IC, int KS,
                          int oc_str, int ic_str, int k_str, int total) {
    int i = blockIdx.x * 256 + threadIdx.x;
    if (i >= total) return;
    int grp = KS / 4;
    int j = i % grp;
    int oc = (i / grp) % OC;
    int g = (i / (grp * OC)) & 3;
    int chunk = i / (grp * OC * 4);
    int CPK = IC / KS;
    int cc = chunk % CPK;
    int khw = chunk / CPK;
    int ic = cc * KS + g * grp + j;
    dst[i] = __float2half(src[(long)oc * oc_str + (long)ic * ic_str + khw * k_str]);
}

// ---- conv0: 1->16 ch, VALU, NHWC f16 out ------------------------------------------
__global__ __launch_bounds__(256) void conv0_k(const float* __restrict__ in,
                                               const float* __restrict__ wT,
                                               const float* __restrict__ bias,
                                               __half* __restrict__ out) {
    __shared__ float wsm[9][16];
    __shared__ float bs[16];
    int tid = threadIdx.x;
    if (tid < 144) wsm[tid / 16][tid % 16] = wT[tid];
    if (tid < 16) bs[tid] = bias[tid];
    __syncthreads();
    int gid = blockIdx.x * 256 + tid;
    int ow = gid % 27;
    int t = (gid / 27) % 256;
    int bf = gid / (27 * 256);
    float acc[16];
#pragma unroll
    for (int o = 0; o < 16; o++) acc[o] = bs[o];
    int iw0 = ow * 3 - 1;
#pragma unroll
    for (int kh = 0; kh < 3; kh++) {
        int tt = t + kh - 1;
        if ((unsigned)tt >= 256u) continue;
        const float* ip = in + ((long)bf * 256 + tt) * 81;
#pragma unroll
        for (int kw = 0; kw < 3; kw++) {
            int iw = iw0 + kw;
            if ((unsigned)iw >= 81u) continue;
            float x = ip[iw];
#pragma unroll
            for (int o = 0; o < 16; o++) acc[o] += x * wsm[kh * 3 + kw][o];
        }
    }
    __half2* op = (__half2*)(out + (long)gid * 16);
#pragma unroll
    for (int o = 0; o < 8; o++)
        op[o] = __floats2half2_rn(fmaxf(acc[2 * o], 0.f), fmaxf(acc[2 * o + 1], 0.f));
}

// ---- MFMA implicit-GEMM conv: NHWC f16 in/out -------------------------------------
template<int IC, int OC, int WIN, int WOUT, int KS>
__global__ __launch_bounds__(256) void convM_k(const __half* __restrict__ in,
                                               const __half* __restrict__ wp,
                                               const float* __restrict__ bias,
                                               __half* __restrict__ out) {
    constexpr int NT = OC / 16;
    constexpr int CPK = IC / KS;
    constexpr int NCHUNK = 9 * CPK;
    constexpr int GRP = KS / 4;
    int tid = threadIdx.x;
    int lane = tid & 63;
    int wv = tid >> 6;
    int l15 = lane & 15;
    int g = lane >> 4;
    int m = blockIdx.x * 64 + wv * 16 + l15;
    int ow = m % WOUT;
    int t = (m / WOUT) % 256;
    int bf = m / (WOUT * 256);

    f4_t acc[NT];
#pragma unroll
    for (int nt = 0; nt < NT; nt++)
#pragma unroll
        for (int r = 0; r < 4; r++) acc[nt][r] = 0.f;

#pragma unroll
    for (int chunk = 0; chunk < NCHUNK; chunk++) {
        int khw = chunk / CPK, cc = chunk % CPK;
        int kh = khw / 3;
        int kw = khw - kh * 3;
        int tt = t + kh - 1;
        int iw = ow * 3 + kw - 1;
        bool ok = ((unsigned)tt < 256u) && ((unsigned)iw < (unsigned)WIN);
        long aoff = ok ? (((long)(bf * 256 + tt) * WIN + iw) * IC + cc * KS + g * GRP) : 0;
        if constexpr (KS == 32) {
            H8 af;
            af.u = *(const uint4*)(in + aoff);
            if (!ok) af.u = make_uint4(0u, 0u, 0u, 0u);
#pragma unroll
            for (int nt = 0; nt < NT; nt++) {
                H8 bf8;
                bf8.u = *(const uint4*)(wp + ((long)(chunk * 4 + g) * OC + nt * 16 + l15) * GRP);
                acc[nt] = __builtin_amdgcn_mfma_f32_16x16x32_f16(af.v, bf8.v, acc[nt], 0, 0, 0);
            }
        } else {
            H4 af;
            af.u = *(const uint2*)(in + aoff);
            if (!ok) af.u = make_uint2(0u, 0u);
#pragma unroll
            for (int nt = 0; nt < NT; nt++) {
                H4 bf4;
                bf4.u = *(const uint2*)(wp + ((long)(chunk * 4 + g) * OC + nt * 16 + l15) * GRP);
                acc[nt] = __builtin_amdgcn_mfma_f32_16x16x16f16(af.v, bf4.v, acc[nt], 0, 0, 0);
            }
        }
    }
    int orow = blockIdx.x * 64 + wv * 16 + g * 4;
#pragma unroll
    for (int nt = 0; nt < NT; nt++) {
        int oc = nt * 16 + l15;
        float b = bias[oc];
#pragma unroll
        for (int r = 0; r < 4; r++) {
            float v = fmaxf(acc[nt][r] + b, 0.f);
            out[(long)(orow + r) * OC + oc] = __float2half(v);
        }
    }
}

// ---- gates MFMA GEMM: G[row][512] = X[row][128] @ Wih^T + (bih+bhh), f16 out ------
__global__ __launch_bounds__(256) void gates_k(const __half* __restrict__ X,
                                               const __half* __restrict__ wp,
                                               const float* __restrict__ b1,
                                               const float* __restrict__ b2,
                                               __half* __restrict__ G) {
    int tid = threadIdx.x;
    int lane = tid & 63;
    int wv = tid >> 6;
    int l15 = lane & 15;
    int g = lane >> 4;
    long r0 = (long)blockIdx.x * 128 + wv * 32;
    int n0 = blockIdx.y * 128;

    f4_t acc[2][8];
#pragma unroll
    for (int s = 0; s < 2; s++)
#pragma unroll
        for (int nt = 0; nt < 8; nt++)
#pragma unroll
            for (int r = 0; r < 4; r++) acc[s][nt][r] = 0.f;

#pragma unroll
    for (int chunk = 0; chunk < 4; chunk++) {
        H8 a0, a1;
        a0.u = *(const uint4*)(X + (r0 + l15) * 128 + chunk * 32 + g * 8);
        a1.u = *(const uint4*)(X + (r0 + 16 + l15) * 128 + chunk * 32 + g * 8);
#pragma unroll
        for (int nt = 0; nt < 8; nt++) {
            H8 bw;
            bw.u = *(const uint4*)(wp + ((long)(chunk * 4 + g) * 512 + n0 + nt * 16 + l15) * 8);
            acc[0][nt] = __builtin_amdgcn_mfma_f32_16x16x32_f16(a0.v, bw.v, acc[0][nt], 0, 0, 0);
            acc[1][nt] = __builtin_amdgcn_mfma_f32_16x16x32_f16(a1.v, bw.v, acc[1][nt], 0, 0, 0);
        }
    }
#pragma unroll
    for (int nt = 0; nt < 8; nt++) {
        int col = n0 + nt * 16 + l15;
        float bias = b1[col] + b2[col];
#pragma unroll
        for (int s = 0; s < 2; s++) {
            long row = r0 + s * 16 + g * 4;
#pragma unroll
            for (int r = 0; r < 4; r++)
                G[(row + r) * 512 + col] = __float2half(acc[s][nt][r] + bias);
        }
    }
}

// ---- LSTM recurrence via MFMA: 1 block per (dir, chain) ---------------------------
// Z^T[512][1] = Whh[512x128] @ h ; Whh A-frags in registers, h broadcast via LDS.
// Wave w owns gate m-tiles {cls*8 + 2w + s2}; lane computes 1 h (16x replicated N).
__global__ __launch_bounds__(256) void lstm_k(const __half* __restrict__ Gf,
                                              const __half* __restrict__ Gb,
                                              const __half* __restrict__ whhfp,
                                              const __half* __restrict__ whhbp,
                                              __half* __restrict__ flat) {
    int bid = blockIdx.x;
    int b = bid & 255;
    int dir = bid >> 8;
    const __half* G = dir ? Gb : Gf;
    const __half* wp = dir ? whhbp : whhfp;
    int tid = threadIdx.x;
    int w = tid >> 6;
    int lane = tid & 63;
    int l15 = lane & 15;
    int g2 = lane >> 4;
    int r = l15 & 3;
    int s = (l15 >> 2) & 1;
    bool owner = (lane & 8) == 0;
    int hcol = w * 32 + s * 16 + g2 * 4 + r;

    // preload Whh A-frags: 8 m-tiles (cls*2+s2) x 4 k-chunks, 128 VGPRs
    H8 afr[8][4];
#pragma unroll
    for (int cls = 0; cls < 4; cls++)
#pragma unroll
        for (int s2 = 0; s2 < 2; s2++) {
            int tile = cls * 8 + w * 2 + s2;
#pragma unroll
            for (int c = 0; c < 4; c++)
                afr[cls * 2 + s2][c].u =
                    *(const uint4*)(wp + ((long)((c * 4 + g2) * 512 + tile * 16 + l15)) * 8);
        }

    __shared__ __half hbuf[2][128];
    if (tid < 128) hbuf[0][tid] = __float2half(0.f);
    __syncthreads();

    float cstate = 0.f;
    long gbase = (long)b * 256 * 512;
    int stepd = dir ? -1 : 1;
    int ts = dir ? 255 : 0;

    __half gcur[4], gnxt[4];
#pragma unroll
    for (int cls = 0; cls < 4; cls++)
        gcur[cls] = G[gbase + (long)ts * 512 + cls * 128 + hcol];

    for (int t = 0; t < 256; t++) {
        int tsn = (t == 255) ? ts : (ts + stepd);
        // prefetch next step's gate pre-activations (used next iter)
#pragma unroll
        for (int cls = 0; cls < 4; cls++)
            gnxt[cls] = G[gbase + (long)tsn * 512 + cls * 128 + hcol];

        int p = t & 1;
        H8 bfr[4];
#pragma unroll
        for (int c = 0; c < 4; c++)
            bfr[c].u = *(const uint4*)(&hbuf[p][c * 32 + g2 * 8]);

        f4_t acc[8];
#pragma unroll
        for (int ti = 0; ti < 8; ti++)
#pragma unroll
            for (int rr = 0; rr < 4; rr++) acc[ti][rr] = 0.f;
#pragma unroll
        for (int c = 0; c < 4; c++)
#pragma unroll
            for (int ti = 0; ti < 8; ti++)
                acc[ti] = __builtin_amdgcn_mfma_f32_16x16x32_f16(afr[ti][c].v, bfr[c].v,
                                                                 acc[ti], 0, 0, 0);
        // select this lane's z per gate class: acc[cls*2+s] element r, + G
        float z[4];
#pragma unroll
        for (int cls = 0; cls < 4; cls++) {
            f4_t va = acc[cls * 2 + 0];
            f4_t vb = acc[cls * 2 + 1];
            float e0 = s ? vb.x : va.x;
            float e1 = s ? vb.y : va.y;
            float e2 = s ? vb.z : va.z;
            float e3 = s ? vb.w : va.w;
            float lo = (r & 1) ? e1 : e0;
            float hi = (r & 1) ? e3 : e2;
            z[cls] = ((r & 2) ? hi : lo) + __half2float(gcur[cls]);
        }
        float ig = sigmoidf_(z[0]);
        float fg = sigmoidf_(z[1]);
        float gg = tanhf_(z[2]);
        float og = sigmoidf_(z[3]);
        cstate = fg * cstate + ig * gg;
        float h = og * tanhf_(cstate);
        __half hh = __float2half(h);
        if (owner) {
            hbuf[p ^ 1][hcol] = hh;
            flat[(long)b * 65536 + ts * 256 + dir * 128 + hcol] = hh;
        }
        __syncthreads();
#pragma unroll
        for (int cls = 0; cls < 4; cls++) gcur[cls] = gnxt[cls];
        ts = tsn;
    }
}

// ---- FC1 MFMA split-K: z[256][128] += flat16 @ fc1_w16^T --------------------------
__global__ __launch_bounds__(256) void fc1m_k(const __half* __restrict__ flat,
                                              const __half* __restrict__ wp,
                                              float* __restrict__ z) {
    int tid = threadIdx.x;
    int lane = tid & 63;
    int wv = tid >> 6;
    int l15 = lane & 15;
    int g = lane >> 4;
    int m0 = blockIdx.x * 64 + wv * 16;
    long k0 = (long)blockIdx.y * 1024;

    f4_t acc[8];
#pragma unroll
    for (int nt = 0; nt < 8; nt++)
#pragma unroll
        for (int r = 0; r < 4; r++) acc[nt][r] = 0.f;

    for (int c = 0; c < 32; c++) {
        long chunk = (k0 >> 5) + c;
        H8 af;
        af.u = *(const uint4*)(flat + (long)(m0 + l15) * 65536 + k0 + c * 32 + g * 8);
#pragma unroll
        for (int nt = 0; nt < 8; nt++) {
            H8 bw;
            bw.u = *(const uint4*)(wp + ((chunk * 4 + g) * 128 + nt * 16 + l15) * 8);
            acc[nt] = __builtin_amdgcn_mfma_f32_16x16x32_f16(af.v, bw.v, acc[nt], 0, 0, 0);
        }
    }
#pragma unroll
    for (int nt = 0; nt < 8; nt++)
#pragma unroll
        for (int r = 0; r < 4; r++)
            atomicAdd(&z[(m0 + g * 4 + r) * 128 + nt * 16 + l15], acc[nt][r]);
}

__global__ void zero_k(float* __restrict__ p, int n) {
    int i = blockIdx.x * 256 + threadIdx.x;
    if (i < n) p[i] = 0.f;
}

// ---- head -------------------------------------------------------------------------
__global__ __launch_bounds__(256) void head_k(const float* __restrict__ z,
                                              const float* __restrict__ b1,
                                              const float* __restrict__ fsw,
                                              const float* __restrict__ fsb,
                                              float* __restrict__ out) {
    __shared__ float sf[256];
    int r = threadIdx.x;
    float acc = fsb[0];
#pragma unroll
    for (int j4 = 0; j4 < 32; j4++) {
        float4 zv = *(const float4*)&z[r * 128 + j4 * 4];
        float4 bv = *(const float4*)&b1[j4 * 4];
        float4 wv = *(const float4*)&fsw[j4 * 4];
        acc += fmaxf(zv.x + bv.x, 0.f) * wv.x;
        acc += fmaxf(zv.y + bv.y, 0.f) * wv.y;
        acc += fmaxf(zv.z + bv.z, 0.f) * wv.z;
        acc += fmaxf(zv.w + bv.w, 0.f) * wv.w;
    }
    float val = sigmoidf_(acc) * 4.f + 1.f;
    out[16 + r] = val;
    sf[r] = val;
    __syncthreads();
    if (r < 16) {
        float m = 0.f;
#pragma unroll
        for (int f = 0; f < 16; f++) m += sf[r * 16 + f];
        out[r] = m * (1.f / 16.f);
    }
}

extern "C" void kernel_launch(void* const* d_in, const int* in_sizes, int n_in,
                              void* d_out, int out_size, void* d_ws, size_t ws_size,
                              hipStream_t stream) {
    const float* audio = (const float*)d_in[0];
    const float* w0 = (const float*)d_in[2];
    const float* b0 = (const float*)d_in[3];
    const float* w1 = (const float*)d_in[4];
    const float* b1 = (const float*)d_in[5];
    const float* w2 = (const float*)d_in[6];
    const float* b2 = (const float*)d_in[7];
    const float* w3 = (const float*)d_in[8];
    const float* b3 = (const float*)d_in[9];
    const float* Wih_f = (const float*)d_in[10];
    const float* Whh_f = (const float*)d_in[11];
    const float* bih_f = (const float*)d_in[12];
    const float* bhh_f = (const float*)d_in[13];
    const float* Wih_b = (const float*)d_in[14];
    const float* Whh_b = (const float*)d_in[15];
    const float* bih_b = (const float*)d_in[16];
    const float* bhh_b = (const float*)d_in[17];
    const float* fc1_w = (const float*)d_in[18];
    const float* fc1_b = (const float*)d_in[19];
    const float* fs_w = (const float*)d_in[20];
    const float* fs_b = (const float*)d_in[21];
    float* out = (float*)d_out;

    char* ws = (char*)d_ws;
    // lifetimes: out1 dies before Gf; out0 dies before flat16; Gf/Gb die before fc1p
    __half* Gf    = (__half*)(ws);                    // 67.1 MB
    __half* out1  = (__half*)(ws);                    // 37.7 MB (pre-Gf)
    __half* fc1p  = (__half*)(ws);                    // 16.8 MB (post-lstm, in Gf)
    __half* Gb    = (__half*)(ws + 67108864);         // 67.1 MB
    __half* flat16= (__half*)(ws + 134217728);        // 33.6 MB
    __half* out0  = (__half*)(ws + 134217728);        // 56.6 MB (pre-flat16)
    __half* X     = (__half*)(ws + 201326592);        // 16.8 MB
    __half* out2  = (__half*)(ws + 218103808);        // 25.2 MB
    char* rd = ws + 243269632;
    float*  w0t   = (float*)(rd);
    __half* w1p   = (__half*)(rd + 1024);
    __half* w2p   = (__half*)(rd + 10240);
    __half* w3p   = (__half*)(rd + 47104);
    __half* wfp   = (__half*)(rd + 194560);
    __half* wbp   = (__half*)(rd + 325632);
    __half* whhfp = (__half*)(rd + 456704);
    __half* whhbp = (__half*)(rd + 587776);
    float*  zbuf  = (float*)(rd + 718848);

    // weight prep
    transpose_w<<<1, 256, 0, stream>>>(w0, w0t, 16, 1);
    pack_wf16<<<18, 256, 0, stream>>>(w1, w1p, 32, 16, 16, 144, 9, 1, 4608);
    pack_wf16<<<72, 256, 0, stream>>>(w2, w2p, 64, 32, 32, 288, 9, 1, 18432);
    pack_wf16<<<288, 256, 0, stream>>>(w3, w3p, 128, 64, 32, 576, 9, 1, 73728);
    pack_wf16<<<256, 256, 0, stream>>>(Wih_f, wfp, 512, 128, 32, 128, 1, 0, 65536);
    pack_wf16<<<256, 256, 0, stream>>>(Wih_b, wbp, 512, 128, 32, 128, 1, 0, 65536);
    pack_wf16<<<256, 256, 0, stream>>>(Whh_f, whhfp, 512, 128, 32, 128, 1, 0, 65536);
    pack_wf16<<<256, 256, 0, stream>>>(Whh_b, whhbp, 512, 128, 32, 128, 1, 0, 65536);

    // conv chain (NHWC f16)
    conv0_k<<<6912, 256, 0, stream>>>(audio, w0t, b0, out0);
    convM_k<16, 32, 27, 9, 16><<<9216, 256, 0, stream>>>(out0, w1p, b1, out1);
    convM_k<32, 64, 9, 3, 32><<<3072, 256, 0, stream>>>(out1, w2p, b2, out2);
    convM_k<64, 128, 3, 1, 32><<<1024, 256, 0, stream>>>(out2, w3p, b3, X);

    // gates
    gates_k<<<dim3(512, 4), 256, 0, stream>>>(X, wfp, bih_f, bhh_f, Gf);
    gates_k<<<dim3(512, 4), 256, 0, stream>>>(X, wbp, bih_b, bhh_b, Gb);

    // recurrence (MFMA, writes f16 flat)
    lstm_k<<<512, 256, 0, stream>>>(Gf, Gb, whhfp, whhbp, flat16);

    // FC head: pack fc1_w (into dead Gf region), split-K MFMA, head
    pack_wf16<<<32768, 256, 0, stream>>>(fc1_w, fc1p, 128, 65536, 32, 65536, 1, 0, 8388608);
    zero_k<<<128, 256, 0, stream>>>(zbuf, 256 * 128);
    fc1m_k<<<dim3(4, 64), 256, 0, stream>>>(flat16, fc1p, zbuf);
    head_k<<<1, 256, 0, stream>>>(zbuf, fc1_b, fs_w, fs_b, out);
}

// Round 5
// 641.193 us; speedup vs baseline: 3.5355x; 1.0337x over previous
//
#include <hip/hip_runtime.h>
#include <hip/hip_fp16.h>

#define BF 256
#define TSTEPS 256

typedef _Float16 h8_t __attribute__((ext_vector_type(8)));
typedef _Float16 h4_t __attribute__((ext_vector_type(4)));
typedef float f4_t __attribute__((ext_vector_type(4)));

union H8 { uint4 u; h8_t v; };
union H4 { uint2 u; h4_t v; };

static __device__ __forceinline__ float sigmoidf_(float x) {
    return 1.f / (1.f + __expf(-x));
}
static __device__ __forceinline__ float tanhf_(float x) {
    return 1.f - 2.f / (__expf(2.f * x) + 1.f);
}

// ---- w0 transpose: w[oc][0][kh][kw] -> wT[khw][oc] (fp32, tiny) --------------------
__global__ void transpose_w(const float* __restrict__ src, float* __restrict__ dst,
                            int OC, int IC) {
    int i = blockIdx.x * 256 + threadIdx.x;
    int n = OC * IC * 9;
    if (i >= n) return;
    int oc = i / (IC * 9);
    int rem = i % (IC * 9);
    dst[rem * OC + oc] = src[i];
}

// ---- generic f16 MFMA operand pack ------------------------------------------------
// dst[i]: i = ((chunk*4 + g)*OC + oc)*grp + j, grp = KS/4
// value = src[oc*oc_str + ic*ic_str + khw*k_str], ic = cc*KS + g*grp + j,
// chunk = khw*(IC/KS) + cc
__global__ void pack_wf16(const float* __restrict__ src, __half* __restrict__ dst,
                          int OC, int IC, int KS,
                          int oc_str, int ic_str, int k_str, int total) {
    int i = blockIdx.x * 256 + threadIdx.x;
    if (i >= total) return;
    int grp = KS / 4;
    int j = i % grp;
    int oc = (i / grp) % OC;
    int g = (i / (grp * OC)) & 3;
    int chunk = i / (grp * OC * 4);
    int CPK = IC / KS;
    int cc = chunk % CPK;
    int khw = chunk / CPK;
    int ic = cc * KS + g * grp + j;
    dst[i] = __float2half(src[(long)oc * oc_str + (long)ic * ic_str + khw * k_str]);
}

// ---- conv0: 1->16 ch, VALU, NHWC f16 out ------------------------------------------
__global__ __launch_bounds__(256) void conv0_k(const float* __restrict__ in,
                                               const float* __restrict__ wT,
                                               const float* __restrict__ bias,
                                               __half* __restrict__ out) {
    __shared__ float wsm[9][16];
    __shared__ float bs[16];
    int tid = threadIdx.x;
    if (tid < 144) wsm[tid / 16][tid % 16] = wT[tid];
    if (tid < 16) bs[tid] = bias[tid];
    __syncthreads();
    int gid = blockIdx.x * 256 + tid;
    int ow = gid % 27;
    int t = (gid / 27) % 256;
    int bf = gid / (27 * 256);
    float acc[16];
#pragma unroll
    for (int o = 0; o < 16; o++) acc[o] = bs[o];
    int iw0 = ow * 3 - 1;
#pragma unroll
    for (int kh = 0; kh < 3; kh++) {
        int tt = t + kh - 1;
        if ((unsigned)tt >= 256u) continue;
        const float* ip = in + ((long)bf * 256 + tt) * 81;
#pragma unroll
        for (int kw = 0; kw < 3; kw++) {
            int iw = iw0 + kw;
            if ((unsigned)iw >= 81u) continue;
            float x = ip[iw];
#pragma unroll
            for (int o = 0; o < 16; o++) acc[o] += x * wsm[kh * 3 + kw][o];
        }
    }
    __half2* op = (__half2*)(out + (long)gid * 16);
#pragma unroll
    for (int o = 0; o < 8; o++)
        op[o] = __floats2half2_rn(fmaxf(acc[2 * o], 0.f), fmaxf(acc[2 * o + 1], 0.f));
}

// ---- MFMA implicit-GEMM conv: NHWC f16 in/out -------------------------------------
template<int IC, int OC, int WIN, int WOUT, int KS>
__global__ __launch_bounds__(256) void convM_k(const __half* __restrict__ in,
                                               const __half* __restrict__ wp,
                                               const float* __restrict__ bias,
                                               __half* __restrict__ out) {
    constexpr int NT = OC / 16;
    constexpr int CPK = IC / KS;
    constexpr int NCHUNK = 9 * CPK;
    constexpr int GRP = KS / 4;
    int tid = threadIdx.x;
    int lane = tid & 63;
    int wv = tid >> 6;
    int l15 = lane & 15;
    int g = lane >> 4;
    int m = blockIdx.x * 64 + wv * 16 + l15;
    int ow = m % WOUT;
    int t = (m / WOUT) % 256;
    int bf = m / (WOUT * 256);

    f4_t acc[NT];
#pragma unroll
    for (int nt = 0; nt < NT; nt++)
#pragma unroll
        for (int r = 0; r < 4; r++) acc[nt][r] = 0.f;

#pragma unroll
    for (int chunk = 0; chunk < NCHUNK; chunk++) {
        int khw = chunk / CPK, cc = chunk % CPK;
        int kh = khw / 3;
        int kw = khw - kh * 3;
        int tt = t + kh - 1;
        int iw = ow * 3 + kw - 1;
        bool ok = ((unsigned)tt < 256u) && ((unsigned)iw < (unsigned)WIN);
        long aoff = ok ? (((long)(bf * 256 + tt) * WIN + iw) * IC + cc * KS + g * GRP) : 0;
        if constexpr (KS == 32) {
            H8 af;
            af.u = *(const uint4*)(in + aoff);
            if (!ok) af.u = make_uint4(0u, 0u, 0u, 0u);
#pragma unroll
            for (int nt = 0; nt < NT; nt++) {
                H8 bf8;
                bf8.u = *(const uint4*)(wp + ((long)(chunk * 4 + g) * OC + nt * 16 + l15) * GRP);
                acc[nt] = __builtin_amdgcn_mfma_f32_16x16x32_f16(af.v, bf8.v, acc[nt], 0, 0, 0);
            }
        } else {
            H4 af;
            af.u = *(const uint2*)(in + aoff);
            if (!ok) af.u = make_uint2(0u, 0u);
#pragma unroll
            for (int nt = 0; nt < NT; nt++) {
                H4 bf4;
                bf4.u = *(const uint2*)(wp + ((long)(chunk * 4 + g) * OC + nt * 16 + l15) * GRP);
                acc[nt] = __builtin_amdgcn_mfma_f32_16x16x16f16(af.v, bf4.v, acc[nt], 0, 0, 0);
            }
        }
    }
    int orow = blockIdx.x * 64 + wv * 16 + g * 4;
#pragma unroll
    for (int nt = 0; nt < NT; nt++) {
        int oc = nt * 16 + l15;
        float b = bias[oc];
#pragma unroll
        for (int r = 0; r < 4; r++) {
            float v = fmaxf(acc[nt][r] + b, 0.f);
            out[(long)(orow + r) * OC + oc] = __float2half(v);
        }
    }
}

// ---- gates MFMA GEMM: G[row][512] = X[row][128] @ Wih^T + (bih+bhh), f16 out ------
__global__ __launch_bounds__(256) void gates_k(const __half* __restrict__ X,
                                               const __half* __restrict__ wp,
                                               const float* __restrict__ b1,
                                               const float* __restrict__ b2,
                                               __half* __restrict__ G) {
    int tid = threadIdx.x;
    int lane = tid & 63;
    int wv = tid >> 6;
    int l15 = lane & 15;
    int g = lane >> 4;
    long r0 = (long)blockIdx.x * 128 + wv * 32;
    int n0 = blockIdx.y * 128;

    f4_t acc[2][8];
#pragma unroll
    for (int s = 0; s < 2; s++)
#pragma unroll
        for (int nt = 0; nt < 8; nt++)
#pragma unroll
            for (int r = 0; r < 4; r++) acc[s][nt][r] = 0.f;

#pragma unroll
    for (int chunk = 0; chunk < 4; chunk++) {
        H8 a0, a1;
        a0.u = *(const uint4*)(X + (r0 + l15) * 128 + chunk * 32 + g * 8);
        a1.u = *(const uint4*)(X + (r0 + 16 + l15) * 128 + chunk * 32 + g * 8);
#pragma unroll
        for (int nt = 0; nt < 8; nt++) {
            H8 bw;
            bw.u = *(const uint4*)(wp + ((long)(chunk * 4 + g) * 512 + n0 + nt * 16 + l15) * 8);
            acc[0][nt] = __builtin_amdgcn_mfma_f32_16x16x32_f16(a0.v, bw.v, acc[0][nt], 0, 0, 0);
            acc[1][nt] = __builtin_amdgcn_mfma_f32_16x16x32_f16(a1.v, bw.v, acc[1][nt], 0, 0, 0);
        }
    }
#pragma unroll
    for (int nt = 0; nt < 8; nt++) {
        int col = n0 + nt * 16 + l15;
        float bias = b1[col] + b2[col];
#pragma unroll
        for (int s = 0; s < 2; s++) {
            long row = r0 + s * 16 + g * 4;
#pragma unroll
            for (int r = 0; r < 4; r++)
                G[(row + r) * 512 + col] = __float2half(acc[s][nt][r] + bias);
        }
    }
}

// ---- LSTM recurrence: 4 chains/block, 128 blocks x 512 thr, Whh in registers ------
// Wave w owns gate tiles {w, w+8, w+16, w+24} (units w*16..w*16+15, all 4 classes).
// MFMA cols = 4 chains x 4 replicas. Z staged via LDS; activation = 1 pair/thread.
__global__ __launch_bounds__(512, 2) void lstm_k(const __half* __restrict__ Gf,
                                                 const __half* __restrict__ Gb,
                                                 const __half* __restrict__ whhfp,
                                                 const __half* __restrict__ whhbp,
                                                 __half* __restrict__ flat) {
    int bid = blockIdx.x;
    int dir = bid >> 6;
    int b0 = (bid & 63) * 4;
    const __half* G = dir ? Gb : Gf;
    const __half* wp = dir ? whhbp : whhfp;
    int tid = threadIdx.x;
    int w = tid >> 6;
    int lane = tid & 63;
    int l15 = lane & 15;
    int g2 = lane >> 4;
    int chn = l15 & 3;
    bool rep0 = (l15 < 4);

    int aunit = tid & 127;          // activation-phase unit
    int achain = tid >> 7;          // activation-phase chain

    // Whh A-frags: 4 classes x 4 k-chunks = 64 VGPRs
    H8 afr[4][4];
#pragma unroll
    for (int k = 0; k < 4; k++) {
        int gate = k * 128 + w * 16 + l15;
#pragma unroll
        for (int c = 0; c < 4; c++)
            afr[k][c].u = *(const uint4*)(wp + ((long)((c * 4 + g2) * 512 + gate)) * 8);
    }

    __shared__ __half hbuf[2][4][136];
    __shared__ float zs[4][4][132];

    for (int i = tid; i < 4 * 136; i += 512) hbuf[0][i / 136][i % 136] = __float2half(0.f);
    __syncthreads();

    long grow = (long)(b0 + achain) * 256;
    int stepd = dir ? -1 : 1;
    int ts = dir ? 255 : 0;
    __half gpre[4];
#pragma unroll
    for (int k = 0; k < 4; k++)
        gpre[k] = G[(grow + ts) * 512 + k * 128 + aunit];

    float cstate = 0.f;

    for (int t = 0; t < 256; t++) {
        int p = t & 1;
        H8 bfr[4];
#pragma unroll
        for (int c = 0; c < 4; c++)
            bfr[c].u = *(const uint4*)(&hbuf[p][chn][c * 32 + g2 * 8]);

        f4_t acc[4];
#pragma unroll
        for (int k = 0; k < 4; k++)
#pragma unroll
            for (int r = 0; r < 4; r++) acc[k][r] = 0.f;
#pragma unroll
        for (int c = 0; c < 4; c++)
#pragma unroll
            for (int k = 0; k < 4; k++)
                acc[k] = __builtin_amdgcn_mfma_f32_16x16x32_f16(afr[k][c].v, bfr[c].v,
                                                                acc[k], 0, 0, 0);
        if (rep0) {
#pragma unroll
            for (int k = 0; k < 4; k++)
                *(f4_t*)(&zs[k][chn][w * 16 + g2 * 4]) = acc[k];
        }
        __syncthreads();

        // activation: one (unit, chain) pair per thread
        float zi = zs[0][achain][aunit] + __half2float(gpre[0]);
        float zf = zs[1][achain][aunit] + __half2float(gpre[1]);
        float zg = zs[2][achain][aunit] + __half2float(gpre[2]);
        float zo = zs[3][achain][aunit] + __half2float(gpre[3]);
        int tsn = (t == 255) ? ts : (ts + stepd);
#pragma unroll
        for (int k = 0; k < 4; k++)
            gpre[k] = G[(grow + tsn) * 512 + k * 128 + aunit];
        float ig = sigmoidf_(zi), fg = sigmoidf_(zf);
        float gg = tanhf_(zg), og = sigmoidf_(zo);
        cstate = fg * cstate + ig * gg;
        float h = og * tanhf_(cstate);
        __half hh = __float2half(h);
        hbuf[p ^ 1][achain][aunit] = hh;
        flat[(long)(b0 + achain) * 65536 + ts * 256 + dir * 128 + aunit] = hh;
        __syncthreads();
        ts = tsn;
    }
}

// ---- FC1 MFMA split-K: z[256][128] += flat16 @ fc1_w16^T --------------------------
__global__ __launch_bounds__(256) void fc1m_k(const __half* __restrict__ flat,
                                              const __half* __restrict__ wp,
                                              float* __restrict__ z) {
    int tid = threadIdx.x;
    int lane = tid & 63;
    int wv = tid >> 6;
    int l15 = lane & 15;
    int g = lane >> 4;
    int m0 = blockIdx.x * 64 + wv * 16;
    long k0 = (long)blockIdx.y * 1024;

    f4_t acc[8];
#pragma unroll
    for (int nt = 0; nt < 8; nt++)
#pragma unroll
        for (int r = 0; r < 4; r++) acc[nt][r] = 0.f;

    for (int c = 0; c < 32; c++) {
        long chunk = (k0 >> 5) + c;
        H8 af;
        af.u = *(const uint4*)(flat + (long)(m0 + l15) * 65536 + k0 + c * 32 + g * 8);
#pragma unroll
        for (int nt = 0; nt < 8; nt++) {
            H8 bw;
            bw.u = *(const uint4*)(wp + ((chunk * 4 + g) * 128 + nt * 16 + l15) * 8);
            acc[nt] = __builtin_amdgcn_mfma_f32_16x16x32_f16(af.v, bw.v, acc[nt], 0, 0, 0);
        }
    }
#pragma unroll
    for (int nt = 0; nt < 8; nt++)
#pragma unroll
        for (int r = 0; r < 4; r++)
            atomicAdd(&z[(m0 + g * 4 + r) * 128 + nt * 16 + l15], acc[nt][r]);
}

__global__ void zero_k(float* __restrict__ p, int n) {
    int i = blockIdx.x * 256 + threadIdx.x;
    if (i < n) p[i] = 0.f;
}

// ---- head -------------------------------------------------------------------------
__global__ __launch_bounds__(256) void head_k(const float* __restrict__ z,
                                              const float* __restrict__ b1,
                                              const float* __restrict__ fsw,
                                              const float* __restrict__ fsb,
                                              float* __restrict__ out) {
    __shared__ float sf[256];
    int r = threadIdx.x;
    float acc = fsb[0];
#pragma unroll
    for (int j4 = 0; j4 < 32; j4++) {
        float4 zv = *(const float4*)&z[r * 128 + j4 * 4];
        float4 bv = *(const float4*)&b1[j4 * 4];
        float4 wv = *(const float4*)&fsw[j4 * 4];
        acc += fmaxf(zv.x + bv.x, 0.f) * wv.x;
        acc += fmaxf(zv.y + bv.y, 0.f) * wv.y;
        acc += fmaxf(zv.z + bv.z, 0.f) * wv.z;
        acc += fmaxf(zv.w + bv.w, 0.f) * wv.w;
    }
    float val = sigmoidf_(acc) * 4.f + 1.f;
    out[16 + r] = val;
    sf[r] = val;
    __syncthreads();
    if (r < 16) {
        float m = 0.f;
#pragma unroll
        for (int f = 0; f < 16; f++) m += sf[r * 16 + f];
        out[r] = m * (1.f / 16.f);
    }
}

extern "C" void kernel_launch(void* const* d_in, const int* in_sizes, int n_in,
                              void* d_out, int out_size, void* d_ws, size_t ws_size,
                              hipStream_t stream) {
    const float* audio = (const float*)d_in[0];
    const float* w0 = (const float*)d_in[2];
    const float* b0 = (const float*)d_in[3];
    const float* w1 = (const float*)d_in[4];
    const float* b1 = (const float*)d_in[5];
    const float* w2 = (const float*)d_in[6];
    const float* b2 = (const float*)d_in[7];
    const float* w3 = (const float*)d_in[8];
    const float* b3 = (const float*)d_in[9];
    const float* Wih_f = (const float*)d_in[10];
    const float* Whh_f = (const float*)d_in[11];
    const float* bih_f = (const float*)d_in[12];
    const float* bhh_f = (const float*)d_in[13];
    const float* Wih_b = (const float*)d_in[14];
    const float* Whh_b = (const float*)d_in[15];
    const float* bih_b = (const float*)d_in[16];
    const float* bhh_b = (const float*)d_in[17];
    const float* fc1_w = (const float*)d_in[18];
    const float* fc1_b = (const float*)d_in[19];
    const float* fs_w = (const float*)d_in[20];
    const float* fs_b = (const float*)d_in[21];
    float* out = (float*)d_out;

    char* ws = (char*)d_ws;
    // lifetimes: out1 dies before Gf; out0 dies before flat16; Gf/Gb die before fc1p
    __half* Gf    = (__half*)(ws);                    // 67.1 MB
    __half* out1  = (__half*)(ws);                    // 37.7 MB (pre-Gf)
    __half* fc1p  = (__half*)(ws);                    // 16.8 MB (post-lstm, in Gf)
    __half* Gb    = (__half*)(ws + 67108864);         // 67.1 MB
    __half* flat16= (__half*)(ws + 134217728);        // 33.6 MB
    __half* out0  = (__half*)(ws + 134217728);        // 56.6 MB (pre-flat16)
    __half* X     = (__half*)(ws + 201326592);        // 16.8 MB
    __half* out2  = (__half*)(ws + 218103808);        // 25.2 MB
    char* rd = ws + 243269632;
    float*  w0t   = (float*)(rd);
    __half* w1p   = (__half*)(rd + 1024);
    __half* w2p   = (__half*)(rd + 10240);
    __half* w3p   = (__half*)(rd + 47104);
    __half* wfp   = (__half*)(rd + 194560);
    __half* wbp   = (__half*)(rd + 325632);
    __half* whhfp = (__half*)(rd + 456704);
    __half* whhbp = (__half*)(rd + 587776);
    float*  zbuf  = (float*)(rd + 718848);

    // weight prep
    transpose_w<<<1, 256, 0, stream>>>(w0, w0t, 16, 1);
    pack_wf16<<<18, 256, 0, stream>>>(w1, w1p, 32, 16, 16, 144, 9, 1, 4608);
    pack_wf16<<<72, 256, 0, stream>>>(w2, w2p, 64, 32, 32, 288, 9, 1, 18432);
    pack_wf16<<<288, 256, 0, stream>>>(w3, w3p, 128, 64, 32, 576, 9, 1, 73728);
    pack_wf16<<<256, 256, 0, stream>>>(Wih_f, wfp, 512, 128, 32, 128, 1, 0, 65536);
    pack_wf16<<<256, 256, 0, stream>>>(Wih_b, wbp, 512, 128, 32, 128, 1, 0, 65536);
    pack_wf16<<<256, 256, 0, stream>>>(Whh_f, whhfp, 512, 128, 32, 128, 1, 0, 65536);
    pack_wf16<<<256, 256, 0, stream>>>(Whh_b, whhbp, 512, 128, 32, 128, 1, 0, 65536);

    // conv chain (NHWC f16)
    conv0_k<<<6912, 256, 0, stream>>>(audio, w0t, b0, out0);
    convM_k<16, 32, 27, 9, 16><<<9216, 256, 0, stream>>>(out0, w1p, b1, out1);
    convM_k<32, 64, 9, 3, 32><<<3072, 256, 0, stream>>>(out1, w2p, b2, out2);
    convM_k<64, 128, 3, 1, 32><<<1024, 256, 0, stream>>>(out2, w3p, b3, X);

    // gates
    gates_k<<<dim3(512, 4), 256, 0, stream>>>(X, wfp, bih_f, bhh_f, Gf);
    gates_k<<<dim3(512, 4), 256, 0, stream>>>(X, wbp, bih_b, bhh_b, Gb);

    // recurrence (MFMA, Whh in regs, writes f16 flat)
    lstm_k<<<128, 512, 0, stream>>>(Gf, Gb, whhfp, whhbp, flat16);

    // FC head: pack fc1_w (into dead Gf region), split-K MFMA, head
    pack_wf16<<<32768, 256, 0, stream>>>(fc1_w, fc1p, 128, 65536, 32, 65536, 1, 0, 8388608);
    zero_k<<<128, 256, 0, stream>>>(zbuf, 256 * 128);
    fc1m_k<<<dim3(4, 64), 256, 0, stream>>>(flat16, fc1p, zbuf);
    head_k<<<1, 256, 0, stream>>>(zbuf, fc1_b, fs_w, fs_b, out);
}

// Round 6
// 559.527 us; speedup vs baseline: 4.0515x; 1.1460x over previous
//
#include <hip/hip_runtime.h>
#include <hip/hip_fp16.h>

#define BF 256
#define TSTEPS 256

typedef _Float16 h8_t __attribute__((ext_vector_type(8)));
typedef _Float16 h4_t __attribute__((ext_vector_type(4)));
typedef float f4_t __attribute__((ext_vector_type(4)));

union H8 { uint4 u; h8_t v; };
union H4 { uint2 u; h4_t v; };

static __device__ __forceinline__ float sigmoidf_(float x) {
    return 1.f / (1.f + __expf(-x));
}
static __device__ __forceinline__ float tanhf_(float x) {
    return 1.f - 2.f / (__expf(2.f * x) + 1.f);
}

// ---- pack helper: f16 MFMA operand layout -----------------------------------------
// dst[i]: i = ((chunk*4 + g)*OC + oc)*grp + j, grp = KS/4
// value = src[oc*oc_str + ic*ic_str + khw*k_str], ic = cc*KS + g*grp + j,
// chunk = khw*(IC/KS) + cc
static __device__ __forceinline__ void pack_one(const float* __restrict__ src,
                                                __half* __restrict__ dst,
                                                int OC, int IC, int KS,
                                                int oc_str, int ic_str, int k_str, int i) {
    int grp = KS / 4;
    int j = i % grp;
    int oc = (i / grp) % OC;
    int g = (i / (grp * OC)) & 3;
    int chunk = i / (grp * OC * 4);
    int CPK = IC / KS;
    int cc = chunk % CPK;
    int khw = chunk / CPK;
    int ic = cc * KS + g * grp + j;
    dst[i] = __float2half(src[(long)oc * oc_str + (long)ic * ic_str + khw * k_str]);
}

// ---- fused weight prep: all conv/gate/recurrence weights in one launch ------------
__global__ __launch_bounds__(256) void prep_k(
        const float* __restrict__ w0, const float* __restrict__ w1,
        const float* __restrict__ w2, const float* __restrict__ w3,
        const float* __restrict__ Wihf, const float* __restrict__ Wihb,
        const float* __restrict__ Whhf, const float* __restrict__ Whhb,
        float* __restrict__ w0t, __half* __restrict__ w1p,
        __half* __restrict__ w2p, __half* __restrict__ w3p,
        __half* __restrict__ wfp, __half* __restrict__ wbp,
        __half* __restrict__ whhfp, __half* __restrict__ whhbp) {
    int i = blockIdx.x * 256 + threadIdx.x;
    if (i < 144) { int oc = i / 9, rem = i % 9; w0t[rem * 16 + oc] = w0[i]; return; }
    i -= 144;
    if (i < 4608) { pack_one(w1, w1p, 32, 16, 16, 144, 9, 1, i); return; }
    i -= 4608;
    if (i < 18432) { pack_one(w2, w2p, 64, 32, 32, 288, 9, 1, i); return; }
    i -= 18432;
    if (i < 73728) { pack_one(w3, w3p, 128, 64, 32, 576, 9, 1, i); return; }
    i -= 73728;
    if (i < 65536) { pack_one(Wihf, wfp, 512, 128, 32, 128, 1, 0, i); return; }
    i -= 65536;
    if (i < 65536) { pack_one(Wihb, wbp, 512, 128, 32, 128, 1, 0, i); return; }
    i -= 65536;
    if (i < 65536) { pack_one(Whhf, whhfp, 512, 128, 32, 128, 1, 0, i); return; }
    i -= 65536;
    if (i < 65536) { pack_one(Whhb, whhbp, 512, 128, 32, 128, 1, 0, i); return; }
}

// ---- fc1 weight pack (runs after lstm; region aliases dead Gf) --------------------
__global__ void pack_wf16(const float* __restrict__ src, __half* __restrict__ dst,
                          int OC, int IC, int KS,
                          int oc_str, int ic_str, int k_str, int total) {
    int i = blockIdx.x * 256 + threadIdx.x;
    if (i >= total) return;
    pack_one(src, dst, OC, IC, KS, oc_str, ic_str, k_str, i);
}

// ---- conv0: 1->16 ch, VALU, NHWC f16 out ------------------------------------------
__global__ __launch_bounds__(256) void conv0_k(const float* __restrict__ in,
                                               const float* __restrict__ wT,
                                               const float* __restrict__ bias,
                                               __half* __restrict__ out) {
    __shared__ float wsm[9][16];
    __shared__ float bs[16];
    int tid = threadIdx.x;
    if (tid < 144) wsm[tid / 16][tid % 16] = wT[tid];
    if (tid < 16) bs[tid] = bias[tid];
    __syncthreads();
    int gid = blockIdx.x * 256 + tid;
    int ow = gid % 27;
    int t = (gid / 27) % 256;
    int bf = gid / (27 * 256);
    float acc[16];
#pragma unroll
    for (int o = 0; o < 16; o++) acc[o] = bs[o];
    int iw0 = ow * 3 - 1;
#pragma unroll
    for (int kh = 0; kh < 3; kh++) {
        int tt = t + kh - 1;
        if ((unsigned)tt >= 256u) continue;
        const float* ip = in + ((long)bf * 256 + tt) * 81;
#pragma unroll
        for (int kw = 0; kw < 3; kw++) {
            int iw = iw0 + kw;
            if ((unsigned)iw >= 81u) continue;
            float x = ip[iw];
#pragma unroll
            for (int o = 0; o < 16; o++) acc[o] += x * wsm[kh * 3 + kw][o];
        }
    }
    __half2* op = (__half2*)(out + (long)gid * 16);
#pragma unroll
    for (int o = 0; o < 8; o++)
        op[o] = __floats2half2_rn(fmaxf(acc[2 * o], 0.f), fmaxf(acc[2 * o + 1], 0.f));
}

// ---- MFMA implicit-GEMM conv: NHWC f16 in/out -------------------------------------
template<int IC, int OC, int WIN, int WOUT, int KS>
__global__ __launch_bounds__(256) void convM_k(const __half* __restrict__ in,
                                               const __half* __restrict__ wp,
                                               const float* __restrict__ bias,
                                               __half* __restrict__ out) {
    constexpr int NT = OC / 16;
    constexpr int CPK = IC / KS;
    constexpr int NCHUNK = 9 * CPK;
    constexpr int GRP = KS / 4;
    int tid = threadIdx.x;
    int lane = tid & 63;
    int wv = tid >> 6;
    int l15 = lane & 15;
    int g = lane >> 4;
    int m = blockIdx.x * 64 + wv * 16 + l15;
    int ow = m % WOUT;
    int t = (m / WOUT) % 256;
    int bf = m / (WOUT * 256);

    f4_t acc[NT];
#pragma unroll
    for (int nt = 0; nt < NT; nt++)
#pragma unroll
        for (int r = 0; r < 4; r++) acc[nt][r] = 0.f;

#pragma unroll
    for (int chunk = 0; chunk < NCHUNK; chunk++) {
        int khw = chunk / CPK, cc = chunk % CPK;
        int kh = khw / 3;
        int kw = khw - kh * 3;
        int tt = t + kh - 1;
        int iw = ow * 3 + kw - 1;
        bool ok = ((unsigned)tt < 256u) && ((unsigned)iw < (unsigned)WIN);
        long aoff = ok ? (((long)(bf * 256 + tt) * WIN + iw) * IC + cc * KS + g * GRP) : 0;
        if constexpr (KS == 32) {
            H8 af;
            af.u = *(const uint4*)(in + aoff);
            if (!ok) af.u = make_uint4(0u, 0u, 0u, 0u);
#pragma unroll
            for (int nt = 0; nt < NT; nt++) {
                H8 bf8;
                bf8.u = *(const uint4*)(wp + ((long)(chunk * 4 + g) * OC + nt * 16 + l15) * GRP);
                acc[nt] = __builtin_amdgcn_mfma_f32_16x16x32_f16(af.v, bf8.v, acc[nt], 0, 0, 0);
            }
        } else {
            H4 af;
            af.u = *(const uint2*)(in + aoff);
            if (!ok) af.u = make_uint2(0u, 0u);
#pragma unroll
            for (int nt = 0; nt < NT; nt++) {
                H4 bf4;
                bf4.u = *(const uint2*)(wp + ((long)(chunk * 4 + g) * OC + nt * 16 + l15) * GRP);
                acc[nt] = __builtin_amdgcn_mfma_f32_16x16x16f16(af.v, bf4.v, acc[nt], 0, 0, 0);
            }
        }
    }
    int orow = blockIdx.x * 64 + wv * 16 + g * 4;
#pragma unroll
    for (int nt = 0; nt < NT; nt++) {
        int oc = nt * 16 + l15;
        float b = bias[oc];
#pragma unroll
        for (int r = 0; r < 4; r++) {
            float v = fmaxf(acc[nt][r] + b, 0.f);
            out[(long)(orow + r) * OC + oc] = __float2half(v);
        }
    }
}

// ---- gates MFMA GEMM, both dirs in one launch (blockIdx.z = dir) ------------------
__global__ __launch_bounds__(256) void gates_k(const __half* __restrict__ X,
                                               const __half* __restrict__ wpf,
                                               const __half* __restrict__ wpb,
                                               const float* __restrict__ bf1,
                                               const float* __restrict__ bf2,
                                               const float* __restrict__ bb1,
                                               const float* __restrict__ bb2,
                                               __half* __restrict__ Gf,
                                               __half* __restrict__ Gb) {
    int dir = blockIdx.z;
    const __half* wp = dir ? wpb : wpf;
    const float* b1 = dir ? bb1 : bf1;
    const float* b2 = dir ? bb2 : bf2;
    __half* G = dir ? Gb : Gf;
    int tid = threadIdx.x;
    int lane = tid & 63;
    int wv = tid >> 6;
    int l15 = lane & 15;
    int g = lane >> 4;
    long r0 = (long)blockIdx.x * 128 + wv * 32;
    int n0 = blockIdx.y * 128;

    f4_t acc[2][8];
#pragma unroll
    for (int s = 0; s < 2; s++)
#pragma unroll
        for (int nt = 0; nt < 8; nt++)
#pragma unroll
            for (int r = 0; r < 4; r++) acc[s][nt][r] = 0.f;

#pragma unroll
    for (int chunk = 0; chunk < 4; chunk++) {
        H8 a0, a1;
        a0.u = *(const uint4*)(X + (r0 + l15) * 128 + chunk * 32 + g * 8);
        a1.u = *(const uint4*)(X + (r0 + 16 + l15) * 128 + chunk * 32 + g * 8);
#pragma unroll
        for (int nt = 0; nt < 8; nt++) {
            H8 bw;
            bw.u = *(const uint4*)(wp + ((long)(chunk * 4 + g) * 512 + n0 + nt * 16 + l15) * 8);
            acc[0][nt] = __builtin_amdgcn_mfma_f32_16x16x32_f16(a0.v, bw.v, acc[0][nt], 0, 0, 0);
            acc[1][nt] = __builtin_amdgcn_mfma_f32_16x16x32_f16(a1.v, bw.v, acc[1][nt], 0, 0, 0);
        }
    }
#pragma unroll
    for (int nt = 0; nt < 8; nt++) {
        int col = n0 + nt * 16 + l15;
        float bias = b1[col] + b2[col];
#pragma unroll
        for (int s = 0; s < 2; s++) {
            long row = r0 + s * 16 + g * 4;
#pragma unroll
            for (int r = 0; r < 4; r++)
                G[(row + r) * 512 + col] = __float2half(acc[s][nt][r] + bias);
        }
    }
}

// ---- LSTM recurrence: 256 blocks x 512 thr, 2 chains/block, Whh in regs -----------
// Wave w owns units w*16..w*16+15 for ALL 4 gate classes (tiles k*128+w*16).
// MFMA cols: chain = l15>>3 (2 chains x 8 replicas). Lane activates unit
// ua = w*16+g2*4+(l15&3) of its chain entirely from its OWN acc regs ->
// one barrier/step, no z staging in LDS.
__global__ __launch_bounds__(512, 2) void lstm_k(const __half* __restrict__ Gf,
                                                 const __half* __restrict__ Gb,
                                                 const __half* __restrict__ whhfp,
                                                 const __half* __restrict__ whhbp,
                                                 __half* __restrict__ flat) {
    int bid = blockIdx.x;
    int dir = bid >> 7;
    int b0 = (bid & 127) * 2;
    const __half* G = dir ? Gb : Gf;
    const __half* wp = dir ? whhbp : whhfp;
    int tid = threadIdx.x;
    int w = tid >> 6;
    int lane = tid & 63;
    int l15 = lane & 15;
    int g2 = lane >> 4;
    int chn = l15 >> 3;
    int r = l15 & 3;
    bool wr = (l15 & 4) == 0;        // one writer per (chain, unit)
    int ua = w * 16 + g2 * 4 + r;

    // Whh A-frags: 4 classes x 4 k-chunks = 64 VGPRs/lane
    H8 afr[4][4];
#pragma unroll
    for (int k = 0; k < 4; k++) {
        int gate = k * 128 + w * 16 + l15;
#pragma unroll
        for (int c = 0; c < 4; c++)
            afr[k][c].u = *(const uint4*)(wp + ((long)((c * 4 + g2) * 512 + gate)) * 8);
    }

    __shared__ __half hbuf[2][2][128];
    if (tid < 256) hbuf[0][tid >> 7][tid & 127] = __float2half(0.f);
    __syncthreads();

    long grow = (long)(b0 + chn) * 256;
    int stepd = dir ? -1 : 1;
    int ts = dir ? 255 : 0;
    __half gcur[4], gnxt[4];
#pragma unroll
    for (int k = 0; k < 4; k++)
        gcur[k] = G[(grow + ts) * 512 + k * 128 + ua];
    float cstate = 0.f;

    for (int t = 0; t < 256; t++) {
        int tsn = (t == 255) ? ts : (ts + stepd);
#pragma unroll
        for (int k = 0; k < 4; k++)          // prefetch next step's G
            gnxt[k] = G[(grow + tsn) * 512 + k * 128 + ua];

        int p = t & 1;
        H8 bfr[4];
#pragma unroll
        for (int c = 0; c < 4; c++)
            bfr[c].u = *(const uint4*)(&hbuf[p][chn][c * 32 + g2 * 8]);

        f4_t acc[4];
#pragma unroll
        for (int k = 0; k < 4; k++)
#pragma unroll
            for (int rr = 0; rr < 4; rr++) acc[k][rr] = 0.f;
#pragma unroll
        for (int c = 0; c < 4; c++)
#pragma unroll
            for (int k = 0; k < 4; k++)
                acc[k] = __builtin_amdgcn_mfma_f32_16x16x32_f16(afr[k][c].v, bfr[c].v,
                                                                acc[k], 0, 0, 0);
        // in-register z select: element r of this lane's own 4 rows
        float z[4];
#pragma unroll
        for (int k = 0; k < 4; k++) {
            f4_t a = acc[k];
            float lo = (r & 1) ? a[1] : a[0];
            float hi = (r & 1) ? a[3] : a[2];
            z[k] = ((r & 2) ? hi : lo) + __half2float(gcur[k]);
        }
        float ig = sigmoidf_(z[0]), fg = sigmoidf_(z[1]);
        float gg = tanhf_(z[2]), og = sigmoidf_(z[3]);
        cstate = fg * cstate + ig * gg;
        float h = og * tanhf_(cstate);
        __half hh = __float2half(h);
        if (wr) {
            hbuf[p ^ 1][chn][ua] = hh;
            flat[(long)(b0 + chn) * 65536 + ts * 256 + dir * 128 + ua] = hh;
        }
        __syncthreads();
#pragma unroll
        for (int k = 0; k < 4; k++) gcur[k] = gnxt[k];
        ts = tsn;
    }
}

// ---- FC1 MFMA split-K: z[256][128] += flat16 @ fc1_w16^T --------------------------
__global__ __launch_bounds__(256) void fc1m_k(const __half* __restrict__ flat,
                                              const __half* __restrict__ wp,
                                              float* __restrict__ z) {
    int tid = threadIdx.x;
    int lane = tid & 63;
    int wv = tid >> 6;
    int l15 = lane & 15;
    int g = lane >> 4;
    int m0 = blockIdx.x * 64 + wv * 16;
    long k0 = (long)blockIdx.y * 1024;

    f4_t acc[8];
#pragma unroll
    for (int nt = 0; nt < 8; nt++)
#pragma unroll
        for (int r = 0; r < 4; r++) acc[nt][r] = 0.f;

    for (int c = 0; c < 32; c++) {
        long chunk = (k0 >> 5) + c;
        H8 af;
        af.u = *(const uint4*)(flat + (long)(m0 + l15) * 65536 + k0 + c * 32 + g * 8);
#pragma unroll
        for (int nt = 0; nt < 8; nt++) {
            H8 bw;
            bw.u = *(const uint4*)(wp + ((chunk * 4 + g) * 128 + nt * 16 + l15) * 8);
            acc[nt] = __builtin_amdgcn_mfma_f32_16x16x32_f16(af.v, bw.v, acc[nt], 0, 0, 0);
        }
    }
#pragma unroll
    for (int nt = 0; nt < 8; nt++)
#pragma unroll
        for (int r = 0; r < 4; r++)
            atomicAdd(&z[(m0 + g * 4 + r) * 128 + nt * 16 + l15], acc[nt][r]);
}

__global__ void zero_k(float* __restrict__ p, int n) {
    int i = blockIdx.x * 256 + threadIdx.x;
    if (i < n) p[i] = 0.f;
}

// ---- head -------------------------------------------------------------------------
__global__ __launch_bounds__(256) void head_k(const float* __restrict__ z,
                                              const float* __restrict__ b1,
                                              const float* __restrict__ fsw,
                                              const float* __restrict__ fsb,
                                              float* __restrict__ out) {
    __shared__ float sf[256];
    int r = threadIdx.x;
    float acc = fsb[0];
#pragma unroll
    for (int j4 = 0; j4 < 32; j4++) {
        float4 zv = *(const float4*)&z[r * 128 + j4 * 4];
        float4 bv = *(const float4*)&b1[j4 * 4];
        float4 wv = *(const float4*)&fsw[j4 * 4];
        acc += fmaxf(zv.x + bv.x, 0.f) * wv.x;
        acc += fmaxf(zv.y + bv.y, 0.f) * wv.y;
        acc += fmaxf(zv.z + bv.z, 0.f) * wv.z;
        acc += fmaxf(zv.w + bv.w, 0.f) * wv.w;
    }
    float val = sigmoidf_(acc) * 4.f + 1.f;
    out[16 + r] = val;
    sf[r] = val;
    __syncthreads();
    if (r < 16) {
        float m = 0.f;
#pragma unroll
        for (int f = 0; f < 16; f++) m += sf[r * 16 + f];
        out[r] = m * (1.f / 16.f);
    }
}

extern "C" void kernel_launch(void* const* d_in, const int* in_sizes, int n_in,
                              void* d_out, int out_size, void* d_ws, size_t ws_size,
                              hipStream_t stream) {
    const float* audio = (const float*)d_in[0];
    const float* w0 = (const float*)d_in[2];
    const float* b0 = (const float*)d_in[3];
    const float* w1 = (const float*)d_in[4];
    const float* b1 = (const float*)d_in[5];
    const float* w2 = (const float*)d_in[6];
    const float* b2 = (const float*)d_in[7];
    const float* w3 = (const float*)d_in[8];
    const float* b3 = (const float*)d_in[9];
    const float* Wih_f = (const float*)d_in[10];
    const float* Whh_f = (const float*)d_in[11];
    const float* bih_f = (const float*)d_in[12];
    const float* bhh_f = (const float*)d_in[13];
    const float* Wih_b = (const float*)d_in[14];
    const float* Whh_b = (const float*)d_in[15];
    const float* bih_b = (const float*)d_in[16];
    const float* bhh_b = (const float*)d_in[17];
    const float* fc1_w = (const float*)d_in[18];
    const float* fc1_b = (const float*)d_in[19];
    const float* fs_w = (const float*)d_in[20];
    const float* fs_b = (const float*)d_in[21];
    float* out = (float*)d_out;

    char* ws = (char*)d_ws;
    // lifetimes: out1 dies before Gf; out0 dies before flat16; Gf/Gb die before fc1p
    __half* Gf    = (__half*)(ws);                    // 67.1 MB
    __half* out1  = (__half*)(ws);                    // 37.7 MB (pre-Gf)
    __half* fc1p  = (__half*)(ws);                    // 16.8 MB (post-lstm, in Gf)
    __half* Gb    = (__half*)(ws + 67108864);         // 67.1 MB
    __half* flat16= (__half*)(ws + 134217728);        // 33.6 MB
    __half* out0  = (__half*)(ws + 134217728);        // 56.6 MB (pre-flat16)
    __half* X     = (__half*)(ws + 201326592);        // 16.8 MB
    __half* out2  = (__half*)(ws + 218103808);        // 25.2 MB
    char* rd = ws + 243269632;
    float*  w0t   = (float*)(rd);
    __half* w1p   = (__half*)(rd + 1024);
    __half* w2p   = (__half*)(rd + 10240);
    __half* w3p   = (__half*)(rd + 47104);
    __half* wfp   = (__half*)(rd + 194560);
    __half* wbp   = (__half*)(rd + 325632);
    __half* whhfp = (__half*)(rd + 456704);
    __half* whhbp = (__half*)(rd + 587776);
    float*  zbuf  = (float*)(rd + 718848);

    // fused weight prep (1 launch)
    prep_k<<<1403, 256, 0, stream>>>(w0, w1, w2, w3, Wih_f, Wih_b, Whh_f, Whh_b,
                                     w0t, w1p, w2p, w3p, wfp, wbp, whhfp, whhbp);

    // conv chain (NHWC f16)
    conv0_k<<<6912, 256, 0, stream>>>(audio, w0t, b0, out0);
    convM_k<16, 32, 27, 9, 16><<<9216, 256, 0, stream>>>(out0, w1p, b1, out1);
    convM_k<32, 64, 9, 3, 32><<<3072, 256, 0, stream>>>(out1, w2p, b2, out2);
    convM_k<64, 128, 3, 1, 32><<<1024, 256, 0, stream>>>(out2, w3p, b3, X);

    // gates, both directions in one launch
    gates_k<<<dim3(512, 4, 2), 256, 0, stream>>>(X, wfp, wbp, bih_f, bhh_f,
                                                 bih_b, bhh_b, Gf, Gb);

    // recurrence (MFMA, Whh in regs, 1 barrier/step, all 256 CUs)
    lstm_k<<<256, 512, 0, stream>>>(Gf, Gb, whhfp, whhbp, flat16);

    // FC head: pack fc1_w (into dead Gf region), split-K MFMA, head
    pack_wf16<<<32768, 256, 0, stream>>>(fc1_w, fc1p, 128, 65536, 32, 65536, 1, 0, 8388608);
    zero_k<<<128, 256, 0, stream>>>(zbuf, 256 * 128);
    fc1m_k<<<dim3(4, 64), 256, 0, stream>>>(flat16, fc1p, zbuf);
    head_k<<<1, 256, 0, stream>>>(zbuf, fc1_b, fs_w, fs_b, out);
}

// Round 7
// 535.465 us; speedup vs baseline: 4.2335x; 1.0449x over previous
//
#include <hip/hip_runtime.h>
#include <hip/hip_fp16.h>

#define BF 256
#define TSTEPS 256

typedef _Float16 h8_t __attribute__((ext_vector_type(8)));
typedef _Float16 h4_t __attribute__((ext_vector_type(4)));
typedef float f4_t __attribute__((ext_vector_type(4)));

union H8 { uint4 u; h8_t v; };
union H4 { uint2 u; h4_t v; };
union U2H4 { uint2 u; __half h[4]; };

static __device__ __forceinline__ float sigmoidf_(float x) {
    return 1.f / (1.f + __expf(-x));
}
static __device__ __forceinline__ float tanhf_(float x) {
    return 1.f - 2.f / (__expf(2.f * x) + 1.f);
}

// ---- pack helper: f16 MFMA operand layout -----------------------------------------
static __device__ __forceinline__ void pack_one(const float* __restrict__ src,
                                                __half* __restrict__ dst,
                                                int OC, int IC, int KS,
                                                int oc_str, int ic_str, int k_str, int i) {
    int grp = KS / 4;
    int j = i % grp;
    int oc = (i / grp) % OC;
    int g = (i / (grp * OC)) & 3;
    int chunk = i / (grp * OC * 4);
    int CPK = IC / KS;
    int cc = chunk % CPK;
    int khw = chunk / CPK;
    int ic = cc * KS + g * grp + j;
    dst[i] = __float2half(src[(long)oc * oc_str + (long)ic * ic_str + khw * k_str]);
}

// ---- fused weight prep ------------------------------------------------------------
__global__ __launch_bounds__(256) void prep_k(
        const float* __restrict__ w0, const float* __restrict__ w1,
        const float* __restrict__ w2, const float* __restrict__ w3,
        const float* __restrict__ Wihf, const float* __restrict__ Wihb,
        const float* __restrict__ Whhf, const float* __restrict__ Whhb,
        float* __restrict__ w0t, __half* __restrict__ w1p,
        __half* __restrict__ w2p, __half* __restrict__ w3p,
        __half* __restrict__ wfp, __half* __restrict__ wbp,
        __half* __restrict__ whhfp, __half* __restrict__ whhbp) {
    int i = blockIdx.x * 256 + threadIdx.x;
    if (i < 144) { int oc = i / 9, rem = i % 9; w0t[rem * 16 + oc] = w0[i]; return; }
    i -= 144;
    if (i < 4608) { pack_one(w1, w1p, 32, 16, 16, 144, 9, 1, i); return; }
    i -= 4608;
    if (i < 18432) { pack_one(w2, w2p, 64, 32, 32, 288, 9, 1, i); return; }
    i -= 18432;
    if (i < 73728) { pack_one(w3, w3p, 128, 64, 32, 576, 9, 1, i); return; }
    i -= 73728;
    if (i < 65536) { pack_one(Wihf, wfp, 512, 128, 32, 128, 1, 0, i); return; }
    i -= 65536;
    if (i < 65536) { pack_one(Wihb, wbp, 512, 128, 32, 128, 1, 0, i); return; }
    i -= 65536;
    if (i < 65536) { pack_one(Whhf, whhfp, 512, 128, 32, 128, 1, 0, i); return; }
    i -= 65536;
    if (i < 65536) { pack_one(Whhb, whhbp, 512, 128, 32, 128, 1, 0, i); return; }
}

__global__ void pack_wf16(const float* __restrict__ src, __half* __restrict__ dst,
                          int OC, int IC, int KS,
                          int oc_str, int ic_str, int k_str, int total) {
    int i = blockIdx.x * 256 + threadIdx.x;
    if (i >= total) return;
    pack_one(src, dst, OC, IC, KS, oc_str, ic_str, k_str, i);
}

// ---- conv0: 1->16 ch, VALU, NHWC f16 out ------------------------------------------
__global__ __launch_bounds__(256) void conv0_k(const float* __restrict__ in,
                                               const float* __restrict__ wT,
                                               const float* __restrict__ bias,
                                               __half* __restrict__ out) {
    __shared__ float wsm[9][16];
    __shared__ float bs[16];
    int tid = threadIdx.x;
    if (tid < 144) wsm[tid / 16][tid % 16] = wT[tid];
    if (tid < 16) bs[tid] = bias[tid];
    __syncthreads();
    int gid = blockIdx.x * 256 + tid;
    int ow = gid % 27;
    int t = (gid / 27) % 256;
    int bf = gid / (27 * 256);
    float acc[16];
#pragma unroll
    for (int o = 0; o < 16; o++) acc[o] = bs[o];
    int iw0 = ow * 3 - 1;
#pragma unroll
    for (int kh = 0; kh < 3; kh++) {
        int tt = t + kh - 1;
        if ((unsigned)tt >= 256u) continue;
        const float* ip = in + ((long)bf * 256 + tt) * 81;
#pragma unroll
        for (int kw = 0; kw < 3; kw++) {
            int iw = iw0 + kw;
            if ((unsigned)iw >= 81u) continue;
            float x = ip[iw];
#pragma unroll
            for (int o = 0; o < 16; o++) acc[o] += x * wsm[kh * 3 + kw][o];
        }
    }
    __half2* op = (__half2*)(out + (long)gid * 16);
#pragma unroll
    for (int o = 0; o < 8; o++)
        op[o] = __floats2half2_rn(fmaxf(acc[2 * o], 0.f), fmaxf(acc[2 * o + 1], 0.f));
}

// ---- MFMA implicit-GEMM conv: NHWC f16 in/out -------------------------------------
template<int IC, int OC, int WIN, int WOUT, int KS>
__global__ __launch_bounds__(256) void convM_k(const __half* __restrict__ in,
                                               const __half* __restrict__ wp,
                                               const float* __restrict__ bias,
                                               __half* __restrict__ out) {
    constexpr int NT = OC / 16;
    constexpr int CPK = IC / KS;
    constexpr int NCHUNK = 9 * CPK;
    constexpr int GRP = KS / 4;
    int tid = threadIdx.x;
    int lane = tid & 63;
    int wv = tid >> 6;
    int l15 = lane & 15;
    int g = lane >> 4;
    int m = blockIdx.x * 64 + wv * 16 + l15;
    int ow = m % WOUT;
    int t = (m / WOUT) % 256;
    int bf = m / (WOUT * 256);

    f4_t acc[NT];
#pragma unroll
    for (int nt = 0; nt < NT; nt++)
#pragma unroll
        for (int r = 0; r < 4; r++) acc[nt][r] = 0.f;

#pragma unroll
    for (int chunk = 0; chunk < NCHUNK; chunk++) {
        int khw = chunk / CPK, cc = chunk % CPK;
        int kh = khw / 3;
        int kw = khw - kh * 3;
        int tt = t + kh - 1;
        int iw = ow * 3 + kw - 1;
        bool ok = ((unsigned)tt < 256u) && ((unsigned)iw < (unsigned)WIN);
        long aoff = ok ? (((long)(bf * 256 + tt) * WIN + iw) * IC + cc * KS + g * GRP) : 0;
        if constexpr (KS == 32) {
            H8 af;
            af.u = *(const uint4*)(in + aoff);
            if (!ok) af.u = make_uint4(0u, 0u, 0u, 0u);
#pragma unroll
            for (int nt = 0; nt < NT; nt++) {
                H8 bf8;
                bf8.u = *(const uint4*)(wp + ((long)(chunk * 4 + g) * OC + nt * 16 + l15) * GRP);
                acc[nt] = __builtin_amdgcn_mfma_f32_16x16x32_f16(af.v, bf8.v, acc[nt], 0, 0, 0);
            }
        } else {
            H4 af;
            af.u = *(const uint2*)(in + aoff);
            if (!ok) af.u = make_uint2(0u, 0u);
#pragma unroll
            for (int nt = 0; nt < NT; nt++) {
                H4 bf4;
                bf4.u = *(const uint2*)(wp + ((long)(chunk * 4 + g) * OC + nt * 16 + l15) * GRP);
                acc[nt] = __builtin_amdgcn_mfma_f32_16x16x16f16(af.v, bf4.v, acc[nt], 0, 0, 0);
            }
        }
    }
    int orow = blockIdx.x * 64 + wv * 16 + g * 4;
#pragma unroll
    for (int nt = 0; nt < NT; nt++) {
        int oc = nt * 16 + l15;
        float b = bias[oc];
#pragma unroll
        for (int r = 0; r < 4; r++) {
            float v = fmaxf(acc[nt][r] + b, 0.f);
            out[(long)(orow + r) * OC + oc] = __float2half(v);
        }
    }
}

// ---- gates MFMA GEMM, TRANSPOSED output G'[(b*512+gate)*256 + tidx] ---------------
// fwd: tidx = t ; bwd: tidx = 255 - t (so lstm always reads ascending tidx)
__global__ __launch_bounds__(256) void gates_k(const __half* __restrict__ X,
                                               const __half* __restrict__ wpf,
                                               const __half* __restrict__ wpb,
                                               const float* __restrict__ bf1,
                                               const float* __restrict__ bf2,
                                               const float* __restrict__ bb1,
                                               const float* __restrict__ bb2,
                                               __half* __restrict__ Gf,
                                               __half* __restrict__ Gb) {
    int dir = blockIdx.z;
    const __half* wp = dir ? wpb : wpf;
    const float* b1 = dir ? bb1 : bf1;
    const float* b2 = dir ? bb2 : bf2;
    __half* G = dir ? Gb : Gf;
    int tid = threadIdx.x;
    int lane = tid & 63;
    int wv = tid >> 6;
    int l15 = lane & 15;
    int g = lane >> 4;
    long r0 = (long)blockIdx.x * 128 + wv * 32;
    int n0 = blockIdx.y * 128;

    f4_t acc[2][8];
#pragma unroll
    for (int s = 0; s < 2; s++)
#pragma unroll
        for (int nt = 0; nt < 8; nt++)
#pragma unroll
            for (int r = 0; r < 4; r++) acc[s][nt][r] = 0.f;

#pragma unroll
    for (int chunk = 0; chunk < 4; chunk++) {
        H8 a0, a1;
        a0.u = *(const uint4*)(X + (r0 + l15) * 128 + chunk * 32 + g * 8);
        a1.u = *(const uint4*)(X + (r0 + 16 + l15) * 128 + chunk * 32 + g * 8);
#pragma unroll
        for (int nt = 0; nt < 8; nt++) {
            H8 bw;
            bw.u = *(const uint4*)(wp + ((long)(chunk * 4 + g) * 512 + n0 + nt * 16 + l15) * 8);
            acc[0][nt] = __builtin_amdgcn_mfma_f32_16x16x32_f16(a0.v, bw.v, acc[0][nt], 0, 0, 0);
            acc[1][nt] = __builtin_amdgcn_mfma_f32_16x16x32_f16(a1.v, bw.v, acc[1][nt], 0, 0, 0);
        }
    }
    int b = (int)(r0 >> 8);
#pragma unroll
    for (int nt = 0; nt < 8; nt++) {
        int col = n0 + nt * 16 + l15;
        float bias = b1[col] + b2[col];
        long base = ((long)b * 512 + col) * 256;
#pragma unroll
        for (int s = 0; s < 2; s++) {
            int tb = (int)(r0 & 255) + s * 16 + g * 4;
            U2H4 pk;
            if (!dir) {
#pragma unroll
                for (int r = 0; r < 4; r++) pk.h[r] = __float2half(acc[s][nt][r] + bias);
                *(uint2*)(G + base + tb) = pk.u;
            } else {
#pragma unroll
                for (int r = 0; r < 4; r++) pk.h[3 - r] = __float2half(acc[s][nt][r] + bias);
                *(uint2*)(G + base + (252 - tb)) = pk.u;
            }
        }
    }
}

// ---- LSTM recurrence: 256 blocks x 512 thr, gate-split de-dup, transposed G -------
// Wave w owns units w*16..w*16+15 for all 4 gate classes. Cols: chn = l15>>3.
// bit2 = (l15>>2)&1 splits classes: bit2=0 -> {i,f}, bit2=1 -> {g,o};
// two shfl_xor(4) stitch the cell update. Writers: bit2=1 & even r (half2 stores).
__global__ __launch_bounds__(512, 2) void lstm_k(const __half* __restrict__ Gf,
                                                 const __half* __restrict__ Gb,
                                                 const __half* __restrict__ whhfp,
                                                 const __half* __restrict__ whhbp,
                                                 __half* __restrict__ flat) {
    int bid = blockIdx.x;
    int dir = bid >> 7;
    int b0 = (bid & 127) * 2;
    const __half* G = dir ? Gb : Gf;
    const __half* wp = dir ? whhbp : whhfp;
    int tid = threadIdx.x;
    int w = tid >> 6;
    int lane = tid & 63;
    int l15 = lane & 15;
    int g2 = lane >> 4;
    int chn = l15 >> 3;
    int r = l15 & 3;
    int bit2 = (l15 >> 2) & 1;
    int ua = w * 16 + g2 * 4 + r;
    bool wrt = bit2 && ((r & 1) == 0);

    // Whh A-frags: 4 classes x 4 k-chunks = 64 VGPRs/lane
    H8 afr[4][4];
#pragma unroll
    for (int k = 0; k < 4; k++) {
        int gate = k * 128 + w * 16 + l15;
#pragma unroll
        for (int c = 0; c < 4; c++)
            afr[k][c].u = *(const uint4*)(wp + ((long)((c * 4 + g2) * 512 + gate)) * 8);
    }

    __shared__ __align__(16) __half hbuf[2][2][128];
    if (tid < 256) hbuf[0][tid >> 7][tid & 127] = __float2half(0.f);
    __syncthreads();

    // this lane's two gate classes (transposed G rows), 8 steps per 16B load
    const __half* gb0 = G + (((long)(b0 + chn) * 512) + bit2 * 256 + ua) * 256;
    const __half* gb1 = gb0 + 128 * 256;

    float cst = 0.f;
    float ma = bit2 ? 2.f : 1.f;
    float mb = bit2 ? 2.f : 1.f;
    float cb = bit2 ? -1.f : 0.f;
    const f4_t zero4 = {0.f, 0.f, 0.f, 0.f};

    H8 gc0, gc1, gn0, gn1;
    gc0.u = *(const uint4*)(gb0);
    gc1.u = *(const uint4*)(gb1);
    long fbase = (long)(b0 + chn) * 65536 + dir * 128 + ua;

    for (int to = 0; to < 32; to++) {
        if (to < 31) {
            gn0.u = *(const uint4*)(gb0 + (to + 1) * 8);
            gn1.u = *(const uint4*)(gb1 + (to + 1) * 8);
        }
#pragma unroll
        for (int ti = 0; ti < 8; ti++) {
            int s = to * 8 + ti;
            int p = s & 1;
            H8 bfr[4];
#pragma unroll
            for (int c = 0; c < 4; c++)
                bfr[c].u = *(const uint4*)(&hbuf[p][chn][c * 32 + g2 * 8]);

            f4_t acc[4];
#pragma unroll
            for (int k = 0; k < 4; k++)
                acc[k] = __builtin_amdgcn_mfma_f32_16x16x32_f16(afr[k][0].v, bfr[0].v,
                                                                zero4, 0, 0, 0);
#pragma unroll
            for (int c = 1; c < 4; c++)
#pragma unroll
                for (int k = 0; k < 4; k++)
                    acc[k] = __builtin_amdgcn_mfma_f32_16x16x32_f16(afr[k][c].v, bfr[c].v,
                                                                    acc[k], 0, 0, 0);
            // element r of (bit2 ? acc[2],acc[3] : acc[0],acc[1])
            f4_t aA, aB;
#pragma unroll
            for (int e = 0; e < 4; e++) {
                aA[e] = bit2 ? acc[2][e] : acc[0][e];
                aB[e] = bit2 ? acc[3][e] : acc[1][e];
            }
            float loA = (r & 1) ? aA[1] : aA[0];
            float hiA = (r & 1) ? aA[3] : aA[2];
            float eA = (r & 2) ? hiA : loA;
            float loB = (r & 1) ? aB[1] : aB[0];
            float hiB = (r & 1) ? aB[3] : aB[2];
            float eB = (r & 2) ? hiB : loB;

            float za = eA + (float)gc0.v[ti];
            float zb = eB + (float)gc1.v[ti];
            float sa = sigmoidf_(ma * za);
            float fa = sa * mb + cb;            // bit2=0: sigmoid(za); bit2=1: tanh(za)
            float sb = sigmoidf_(zb);           // bit2=0: sigmoid(f); bit2=1: sigmoid(o)
            float grecv = __shfl_xor(fa, 4, 64);
            float cn = sb * cst + fa * grecv;   // valid on bit2=0 lanes
            cst = cn;
            float tc = tanhf_(cn);
            float tcr = __shfl_xor(tc, 4, 64);  // bit2=1 receives tanh(c')
            float h = sb * tcr;                 // valid on bit2=1 lanes
            float hp = __shfl_xor(h, 1, 64);    // partner unit's h
            if (wrt) {
                __half2 h2 = __floats2half2_rn(h, hp);
                int ts = dir ? (255 - s) : s;
                *(__half2*)(&hbuf[p ^ 1][chn][ua]) = h2;
                *(__half2*)(flat + fbase + (long)ts * 256) = h2;
            }
            __syncthreads();
        }
        gc0 = gn0;
        gc1 = gn1;
    }
}

// ---- FC1 MFMA split-K: z[256][128] += flat16 @ fc1_w16^T --------------------------
__global__ __launch_bounds__(256) void fc1m_k(const __half* __restrict__ flat,
                                              const __half* __restrict__ wp,
                                              float* __restrict__ z) {
    int tid = threadIdx.x;
    int lane = tid & 63;
    int wv = tid >> 6;
    int l15 = lane & 15;
    int g = lane >> 4;
    int m0 = blockIdx.x * 64 + wv * 16;
    long k0 = (long)blockIdx.y * 1024;

    f4_t acc[8];
#pragma unroll
    for (int nt = 0; nt < 8; nt++)
#pragma unroll
        for (int r = 0; r < 4; r++) acc[nt][r] = 0.f;

    for (int c = 0; c < 32; c++) {
        long chunk = (k0 >> 5) + c;
        H8 af;
        af.u = *(const uint4*)(flat + (long)(m0 + l15) * 65536 + k0 + c * 32 + g * 8);
#pragma unroll
        for (int nt = 0; nt < 8; nt++) {
            H8 bw;
            bw.u = *(const uint4*)(wp + ((chunk * 4 + g) * 128 + nt * 16 + l15) * 8);
            acc[nt] = __builtin_amdgcn_mfma_f32_16x16x32_f16(af.v, bw.v, acc[nt], 0, 0, 0);
        }
    }
#pragma unroll
    for (int nt = 0; nt < 8; nt++)
#pragma unroll
        for (int r = 0; r < 4; r++)
            atomicAdd(&z[(m0 + g * 4 + r) * 128 + nt * 16 + l15], acc[nt][r]);
}

__global__ void zero_k(float* __restrict__ p, int n) {
    int i = blockIdx.x * 256 + threadIdx.x;
    if (i < n) p[i] = 0.f;
}

// ---- head -------------------------------------------------------------------------
__global__ __launch_bounds__(256) void head_k(const float* __restrict__ z,
                                              const float* __restrict__ b1,
                                              const float* __restrict__ fsw,
                                              const float* __restrict__ fsb,
                                              float* __restrict__ out) {
    __shared__ float sf[256];
    int r = threadIdx.x;
    float acc = fsb[0];
#pragma unroll
    for (int j4 = 0; j4 < 32; j4++) {
        float4 zv = *(const float4*)&z[r * 128 + j4 * 4];
        float4 bv = *(const float4*)&b1[j4 * 4];
        float4 wv = *(const float4*)&fsw[j4 * 4];
        acc += fmaxf(zv.x + bv.x, 0.f) * wv.x;
        acc += fmaxf(zv.y + bv.y, 0.f) * wv.y;
        acc += fmaxf(zv.z + bv.z, 0.f) * wv.z;
        acc += fmaxf(zv.w + bv.w, 0.f) * wv.w;
    }
    float val = sigmoidf_(acc) * 4.f + 1.f;
    out[16 + r] = val;
    sf[r] = val;
    __syncthreads();
    if (r < 16) {
        float m = 0.f;
#pragma unroll
        for (int f = 0; f < 16; f++) m += sf[r * 16 + f];
        out[r] = m * (1.f / 16.f);
    }
}

extern "C" void kernel_launch(void* const* d_in, const int* in_sizes, int n_in,
                              void* d_out, int out_size, void* d_ws, size_t ws_size,
                              hipStream_t stream) {
    const float* audio = (const float*)d_in[0];
    const float* w0 = (const float*)d_in[2];
    const float* b0 = (const float*)d_in[3];
    const float* w1 = (const float*)d_in[4];
    const float* b1 = (const float*)d_in[5];
    const float* w2 = (const float*)d_in[6];
    const float* b2 = (const float*)d_in[7];
    const float* w3 = (const float*)d_in[8];
    const float* b3 = (const float*)d_in[9];
    const float* Wih_f = (const float*)d_in[10];
    const float* Whh_f = (const float*)d_in[11];
    const float* bih_f = (const float*)d_in[12];
    const float* bhh_f = (const float*)d_in[13];
    const float* Wih_b = (const float*)d_in[14];
    const float* Whh_b = (const float*)d_in[15];
    const float* bih_b = (const float*)d_in[16];
    const float* bhh_b = (const float*)d_in[17];
    const float* fc1_w = (const float*)d_in[18];
    const float* fc1_b = (const float*)d_in[19];
    const float* fs_w = (const float*)d_in[20];
    const float* fs_b = (const float*)d_in[21];
    float* out = (float*)d_out;

    char* ws = (char*)d_ws;
    // lifetimes: out1 dies before Gf; out0 dies before flat16; Gf/Gb die before fc1p
    __half* Gf    = (__half*)(ws);                    // 67.1 MB (transposed layout)
    __half* out1  = (__half*)(ws);                    // 37.7 MB (pre-Gf)
    __half* fc1p  = (__half*)(ws);                    // 16.8 MB (post-lstm, in Gf)
    __half* Gb    = (__half*)(ws + 67108864);         // 67.1 MB
    __half* flat16= (__half*)(ws + 134217728);        // 33.6 MB
    __half* out0  = (__half*)(ws + 134217728);        // 56.6 MB (pre-flat16)
    __half* X     = (__half*)(ws + 201326592);        // 16.8 MB
    __half* out2  = (__half*)(ws + 218103808);        // 25.2 MB
    char* rd = ws + 243269632;
    float*  w0t   = (float*)(rd);
    __half* w1p   = (__half*)(rd + 1024);
    __half* w2p   = (__half*)(rd + 10240);
    __half* w3p   = (__half*)(rd + 47104);
    __half* wfp   = (__half*)(rd + 194560);
    __half* wbp   = (__half*)(rd + 325632);
    __half* whhfp = (__half*)(rd + 456704);
    __half* whhbp = (__half*)(rd + 587776);
    float*  zbuf  = (float*)(rd + 718848);

    // fused weight prep (1 launch)
    prep_k<<<1403, 256, 0, stream>>>(w0, w1, w2, w3, Wih_f, Wih_b, Whh_f, Whh_b,
                                     w0t, w1p, w2p, w3p, wfp, wbp, whhfp, whhbp);

    // conv chain (NHWC f16)
    conv0_k<<<6912, 256, 0, stream>>>(audio, w0t, b0, out0);
    convM_k<16, 32, 27, 9, 16><<<9216, 256, 0, stream>>>(out0, w1p, b1, out1);
    convM_k<32, 64, 9, 3, 32><<<3072, 256, 0, stream>>>(out1, w2p, b2, out2);
    convM_k<64, 128, 3, 1, 32><<<1024, 256, 0, stream>>>(out2, w3p, b3, X);

    // gates, both directions, transposed G output
    gates_k<<<dim3(512, 4, 2), 256, 0, stream>>>(X, wfp, wbp, bih_f, bhh_f,
                                                 bih_b, bhh_b, Gf, Gb);

    // recurrence (MFMA + gate-split de-dup, 1 barrier/step)
    lstm_k<<<256, 512, 0, stream>>>(Gf, Gb, whhfp, whhbp, flat16);

    // FC head: pack fc1_w (into dead Gf region), split-K MFMA, head
    pack_wf16<<<32768, 256, 0, stream>>>(fc1_w, fc1p, 128, 65536, 32, 65536, 1, 0, 8388608);
    zero_k<<<128, 256, 0, stream>>>(zbuf, 256 * 128);
    fc1m_k<<<dim3(4, 64), 256, 0, stream>>>(flat16, fc1p, zbuf);
    head_k<<<1, 256, 0, stream>>>(zbuf, fc1_b, fs_w, fs_b, out);
}